// Round 5
// baseline (315.782 us; speedup 1.0000x reference)
//
#include <hip/hip_runtime.h>
#include <cstdint>
#include <cstddef>

#define BB 16
#define CC 512
#define NN 4096

typedef __attribute__((ext_vector_type(4))) float f32x4;
typedef __attribute__((ext_vector_type(8))) short bf16x8;

#define VMCNT(n) asm volatile("s_waitcnt vmcnt(" #n ")" ::: "memory")

__device__ __forceinline__ unsigned short f2bf(float f) {
  unsigned int u = __float_as_uint(f);
  u += 0x7FFFu + ((u >> 16) & 1u);   // round-to-nearest-even
  return (unsigned short)(u >> 16);
}
__device__ __forceinline__ float bf2f(unsigned short h) {
  return __uint_as_float(((unsigned int)h) << 16);
}

// async global->LDS, 16B per lane. LDS dest must be wave-uniform base; HW adds lane*16.
__device__ __forceinline__ void gload16(const unsigned short* g, short* l) {
  __builtin_amdgcn_global_load_lds(
      (const __attribute__((address_space(1))) unsigned int*)g,
      (__attribute__((address_space(3))) unsigned int*)(__attribute__((address_space(3))) short*)l,
      16, 0, 0);
}

// ---------------- Kernel A: x -> bf16 hi/lo, transposed hi, row partial sums ----------
__global__ __launch_bounds__(256) void k_convert(
    const float* __restrict__ x,
    unsigned short* __restrict__ qhi,
    unsigned short* __restrict__ qlo,
    unsigned short* __restrict__ qt,
    float* __restrict__ part)
{
  const int nt = blockIdx.x;     // 16 tiles of 256 n
  const int ct = blockIdx.y;     // 8 tiles of 64 c
  const int b  = blockIdx.z;
  const int c0 = ct << 6;
  const int n0 = nt << 8;
  const int t  = threadIdx.x;
  const int w  = t >> 6;
  const int l  = t & 63;

  __shared__ unsigned short lt[256 * 65];   // [n_local][c_local], pitch 65 (bank spread)
  __shared__ float rsum[64];

  const size_t xb = (size_t)b * CC * NN;

  for (int i = 0; i < 16; ++i) {
    const int r = (i << 2) + w;                       // c row in tile (wave-uniform)
    const size_t off = xb + (size_t)(c0 + r) * NN + n0 + (l << 2);
    const float4 v = *(const float4*)(x + off);
    const unsigned short h0 = f2bf(v.x), h1 = f2bf(v.y), h2 = f2bf(v.z), h3 = f2bf(v.w);
    const unsigned short g0 = f2bf(v.x - bf2f(h0)), g1 = f2bf(v.y - bf2f(h1)),
                         g2 = f2bf(v.z - bf2f(h2)), g3 = f2bf(v.w - bf2f(h3));
    *(ushort4*)(qhi + off) = make_ushort4(h0, h1, h2, h3);
    *(ushort4*)(qlo + off) = make_ushort4(g0, g1, g2, g3);
    const int nl = l << 2;
    lt[(nl + 0) * 65 + r] = h0;
    lt[(nl + 1) * 65 + r] = h1;
    lt[(nl + 2) * 65 + r] = h2;
    lt[(nl + 3) * 65 + r] = h3;
    float s = v.x + v.y + v.z + v.w;
    #pragma unroll
    for (int o = 32; o > 0; o >>= 1) s += __shfl_down(s, o);
    if (l == 0) rsum[r] = s;                          // each wave owns distinct rows
  }
  __syncthreads();
  if (t < 64) part[((size_t)b * CC + c0 + t) * 16 + nt] = rsum[t];

  // transposed write: qt[b][n][c]
  #pragma unroll
  for (int p = 0; p < 8; ++p) {
    const int n   = (p << 5) + (t >> 3);
    const int cc8 = (t & 7) << 3;
    const unsigned short* e = &lt[n * 65 + cc8];
    uint4 pk;
    pk.x = (unsigned)e[0] | ((unsigned)e[1] << 16);
    pk.y = (unsigned)e[2] | ((unsigned)e[3] << 16);
    pk.z = (unsigned)e[4] | ((unsigned)e[5] << 16);
    pk.w = (unsigned)e[6] | ((unsigned)e[7] << 16);
    *(uint4*)(qt + ((size_t)b * NN + n0 + n) * CC + c0 + cc8) = pk;
  }
}

// ---------------- Kernel A2: sum row partials -> pooled_x raw sums --------------------
__global__ __launch_bounds__(256) void k_sumpart(const float* __restrict__ part,
                                                 float* __restrict__ px)
{
  const int g = blockIdx.x * 256 + threadIdx.x;   // 0..8191 = b*512+c
  float s = 0.f;
  #pragma unroll
  for (int i = 0; i < 16; ++i) s += part[(size_t)g * 16 + i];
  px[g] = s;
}

// ---------------- Kernel B: energy = HH+HL+LH into ONE acc, SYMMETRIC upper-tri ------
// 128x128 tile, 4 waves, BK=32. Depth-2 pipeline (3 buffers): per iter, stage(kk+2)
// issues; VMCNT(8) BEFORE the barrier guarantees every wave's stage(kk+1) landed when
// any wave passes the barrier (sound cross-wave), while stage(kk+2)'s 8 loads stay in
// flight across it (T4).
template <int KSPLIT>
__global__ __launch_bounds__(256, 1) void k_energy(
    const unsigned short* __restrict__ qhi,
    const unsigned short* __restrict__ qlo,
    float* __restrict__ EP)
{
  const int bx  = blockIdx.x;               // 160*KSPLIT blocks
  const int xcd = bx & 7;
  const int j   = bx >> 3;
  const int gi  = j / 10;
  const int t10 = j % 10;
  const int g   = xcd + (gi << 3);          // group = b*KSPLIT+ks, grouped per XCD
  const int b   = g / KSPLIT;
  const int ks  = g % KSPLIT;
  int tr, tc;
  if (t10 < 4)      { tr = 0; tc = t10; }
  else if (t10 < 7) { tr = 1; tc = t10 - 3; }
  else if (t10 < 9) { tr = 2; tc = t10 - 5; }
  else              { tr = 3; tc = 3; }
  const bool diag = (tr == tc);
  const int kbase = ks * (NN / KSPLIT);
  const int NK    = 128 / KSPLIT;           // K-steps of 32

  const int t = threadIdx.x, w = t >> 6, l = t & 63;
  const int wr = w >> 1, wc = w & 1;

  __shared__ short lds[3][4][128 * 32];     // [buf][Ahi,Alo,Bhi,Blo] = 96 KiB

  const size_t qoff = (size_t)b * CC * NN;
  const unsigned short* sAh = qhi + qoff + (size_t)(tr * 128) * NN;
  const unsigned short* sAl = qlo + qoff + (size_t)(tr * 128) * NN;
  const unsigned short* sBh = diag ? sAh : qhi + qoff + (size_t)(tc * 128) * NN;
  const unsigned short* sBl = diag ? sAl : qlo + qoff + (size_t)(tc * 128) * NN;

  // staging: chunk = w*64+l; row = chunk>>2; stored kchunk = chunk&3;
  // logical kchunk = stored ^ ((row>>2)&3)  (XOR swizzle, pre-swizzled source)
  const int r1 = w * 16 + (l >> 2);
  const int kl = (((l & 3) ^ (l >> 4)) << 3);          // logical k elem offset
  const int d1 = w * 512;                               // LDS short offset (wave-uniform)
  const int d2 = 2048 + w * 512;

  // fragment read: row = base + (l&15); logical chunk = l>>4; stored = logical ^ ((row>>2)&3)
  const int laneoff = ((l & 15) << 5) + ((((l >> 4) ^ ((l >> 2) & 3))) << 3);

  f32x4 acc[4][4] = {};

  auto stage = [&](int buf, int kk) {       // always 8 loads (uniform vmcnt)
    const int k0 = kbase + kk * 32 + kl;
    gload16(sAh + (size_t)r1 * NN + k0,        &lds[buf][0][d1]);
    gload16(sAh + (size_t)(r1 + 64) * NN + k0, &lds[buf][0][d2]);
    gload16(sAl + (size_t)r1 * NN + k0,        &lds[buf][1][d1]);
    gload16(sAl + (size_t)(r1 + 64) * NN + k0, &lds[buf][1][d2]);
    gload16(sBh + (size_t)r1 * NN + k0,        &lds[buf][2][d1]);
    gload16(sBh + (size_t)(r1 + 64) * NN + k0, &lds[buf][2][d2]);
    gload16(sBl + (size_t)r1 * NN + k0,        &lds[buf][3][d1]);
    gload16(sBl + (size_t)(r1 + 64) * NN + k0, &lds[buf][3][d2]);
  };

  stage(0, 0);
  stage(1, 1);
  VMCNT(8);                                 // stage(0) landed (own wave)
  __builtin_amdgcn_s_barrier();             // -> stage(0) landed for ALL waves

  for (int kk = 0; kk < NK; ++kk) {
    const int cur = kk % 3;
    if (kk + 2 < NK) stage((kk + 2) % 3, kk + 2);   // overwrites buf read at kk-1 (barrier-protected)
    const short* Ah = &lds[cur][0][0];
    const short* Al = &lds[cur][1][0];
    const short* Bh = &lds[cur][2][0];
    const short* Bl = &lds[cur][3][0];
    bf16x8 ah[4], al[4], bh[4], bl[4];
    #pragma unroll
    for (int m = 0; m < 4; ++m) {
      const int off = (wr * 64 + m * 16) * 32 + laneoff;
      ah[m] = *(const bf16x8*)(Ah + off);
      al[m] = *(const bf16x8*)(Al + off);
    }
    #pragma unroll
    for (int n = 0; n < 4; ++n) {
      const int off = (wc * 64 + n * 16) * 32 + laneoff;
      bh[n] = *(const bf16x8*)(Bh + off);
      bl[n] = *(const bf16x8*)(Bl + off);
    }
    __builtin_amdgcn_s_setprio(1);
    #pragma unroll
    for (int m = 0; m < 4; ++m)
      #pragma unroll
      for (int n = 0; n < 4; ++n) {
        acc[m][n] = __builtin_amdgcn_mfma_f32_16x16x32_bf16(ah[m], bh[n], acc[m][n], 0, 0, 0);
        acc[m][n] = __builtin_amdgcn_mfma_f32_16x16x32_bf16(ah[m], bl[n], acc[m][n], 0, 0, 0);
        acc[m][n] = __builtin_amdgcn_mfma_f32_16x16x32_bf16(al[m], bh[n], acc[m][n], 0, 0, 0);
      }
    __builtin_amdgcn_s_setprio(0);
    if (kk + 2 < NK)      VMCNT(8);   // stage(kk+1) landed; stage(kk+2) in flight
    else if (kk + 1 < NK) VMCNT(0);   // drain last prefetch
    __builtin_amdgcn_s_barrier();
  }

  const int row0 = tr * 128 + wr * 64, col0 = tc * 128 + wc * 64;
  float* Eb = EP + ((size_t)ks * BB + b) * CC * CC;
  #pragma unroll
  for (int m = 0; m < 4; ++m)
    #pragma unroll
    for (int n = 0; n < 4; ++n)
      #pragma unroll
      for (int r = 0; r < 4; ++r) {
        const int row = row0 + m * 16 + ((l >> 4) << 2) + r;   // C/D: row=(lane>>4)*4+reg
        const int col = col0 + n * 16 + (l & 15);              //      col=lane&15
        const float v = acc[m][n][r];
        Eb[(size_t)row * CC + col] = v;
        if (!diag) Eb[(size_t)col * CC + row] = v;   // mirror (L2 merges the scatter)
      }
}

// ---------------- Kernel C: att = softmax(-E) per row; pooled_out = att . mean_x ------
template <int NP>
__global__ __launch_bounds__(64) void k_softmax(
    const float* __restrict__ EP, const float* __restrict__ px,
    unsigned short* __restrict__ att, float* __restrict__ po)
{
  const int bx = blockIdx.x;                  // 8192 = b*512+c
  const int b = bx >> 9, c = bx & 511;
  const int l = threadIdx.x;
  const size_t rowoff = ((size_t)b * CC + c) * CC;
  const size_t PS = (size_t)BB * CC * CC;
  float v[8];
  float mn = 1e30f;
  #pragma unroll
  for (int i = 0; i < 8; ++i) {
    float s = EP[rowoff + l + i * 64];
    #pragma unroll
    for (int p = 1; p < NP; ++p) s += EP[p * PS + rowoff + l + i * 64];
    v[i] = s; mn = fminf(mn, s);
  }
  #pragma unroll
  for (int o = 32; o > 0; o >>= 1) mn = fminf(mn, __shfl_xor(mn, o));
  float s = 0.f;
  #pragma unroll
  for (int i = 0; i < 8; ++i) { v[i] = __expf(mn - v[i]); s += v[i]; }
  float dot = 0.f;
  const float* pxb = px + (size_t)b * CC;
  #pragma unroll
  for (int i = 0; i < 8; ++i) dot += v[i] * pxb[l + i * 64];
  #pragma unroll
  for (int o = 32; o > 0; o >>= 1) { s += __shfl_xor(s, o); dot += __shfl_xor(dot, o); }
  const float inv = 1.f / s;
  unsigned short* arow = att + ((size_t)b * CC + c) * CC;
  #pragma unroll
  for (int i = 0; i < 8; ++i) arow[l + i * 64] = f2bf(v[i] * inv);
  if (l == 0) po[(size_t)b * CC + c] = dot / (s * 4096.f);
}

// ---------------- Kernel D: SE MLP -> se[b][c] -----------------------------------------
__global__ __launch_bounds__(256) void k_mlp(
    const float* __restrict__ px, const float* __restrict__ po,
    const float* __restrict__ w1, const float* __restrict__ b1,
    const float* __restrict__ w2, const float* __restrict__ b2,
    float* __restrict__ se)
{
  const int b = blockIdx.x, t = threadIdx.x;
  __shared__ float p[1024];
  __shared__ float hp[64][5];
  __shared__ float h[64];
  for (int i = t; i < 1024; i += 256)
    p[i] = (i < 512) ? px[(size_t)b * 512 + i] * (1.f / 4096.f)
                     : po[(size_t)b * 512 + i - 512];
  __syncthreads();
  {
    const int j = t >> 2, q = t & 3;
    float s = 0.f;
    const float* wr = w1 + (size_t)j * 1024 + q * 256;
    const float* pp = p + q * 256;
    for (int k = 0; k < 256; ++k) s += pp[k] * wr[k];
    hp[j][q] = s;
  }
  __syncthreads();
  if (t < 64) h[t] = fmaxf(hp[t][0] + hp[t][1] + hp[t][2] + hp[t][3] + b1[t], 0.f);
  __syncthreads();
  for (int c = t; c < 512; c += 256) {
    float s = b2[c];
    for (int j = 0; j < 64; ++j) s += h[j] * w2[(size_t)c * 64 + j];
    se[(size_t)b * 512 + c] = 1.f / (1.f + __expf(-s));
  }
}

// ---------------- Kernel E: out = att @ q, fused blend se*x + (1-se)*out --------------
// Depth-2 pipeline (3 buffers), VMCNT(4) before each barrier. Blend reads qhi.
__global__ __launch_bounds__(256) void k_out(
    const unsigned short* __restrict__ att,
    const unsigned short* __restrict__ qt,
    const float* __restrict__ se,
    const unsigned short* __restrict__ qhi,
    float* __restrict__ out)
{
  const int bx = blockIdx.x;                      // 2048 blocks, XCD-grouped per batch
  const int xcd = bx & 7;
  const int j   = bx >> 3;                        // 0..255
  const int b   = xcd + ((j >> 7) << 3);          // 0..15, one batch's 128 tiles per XCD
  const int tt  = j & 127;
  const int tr = tt >> 5, tc = tt & 31;
  const int t = threadIdx.x, w = t >> 6, l = t & 63;
  const int wr = w >> 1, wc = w & 1;

  __shared__ short lds[3][2][128 * 32];           // 48 KiB (reused as epilogue slabs)

  const unsigned short* sA = att + (size_t)b * CC * CC + (size_t)(tr * 128) * CC;
  const unsigned short* sB = qt  + (size_t)b * NN * CC + (size_t)(tc * 128) * CC;

  const int r1 = w * 16 + (l >> 2);
  const int kl = (((l & 3) ^ (l >> 4)) << 3);
  const int d1 = w * 512, d2 = 2048 + w * 512;
  const int laneoff = ((l & 15) << 5) + ((((l >> 4) ^ ((l >> 2) & 3))) << 3);

  f32x4 acc[4][4] = {};

  auto stage = [&](int buf, int kk) {             // 4 loads
    const int k0 = kk * 32 + kl;
    gload16(sA + (size_t)r1 * CC + k0,        &lds[buf][0][d1]);
    gload16(sA + (size_t)(r1 + 64) * CC + k0, &lds[buf][0][d2]);
    gload16(sB + (size_t)r1 * CC + k0,        &lds[buf][1][d1]);
    gload16(sB + (size_t)(r1 + 64) * CC + k0, &lds[buf][1][d2]);
  };

  stage(0, 0);
  stage(1, 1);
  VMCNT(4);                                 // stage(0) landed (own wave)
  __builtin_amdgcn_s_barrier();             // -> landed for all waves

  for (int kk = 0; kk < 16; ++kk) {
    const int cur = kk % 3;
    if (kk + 2 < 16) stage((kk + 2) % 3, kk + 2);
    const short* A  = &lds[cur][0][0];
    const short* Bm = &lds[cur][1][0];
    bf16x8 af[4], bf[4];
    #pragma unroll
    for (int m = 0; m < 4; ++m) af[m] = *(const bf16x8*)(A  + (wr * 64 + m * 16) * 32 + laneoff);
    #pragma unroll
    for (int n = 0; n < 4; ++n) bf[n] = *(const bf16x8*)(Bm + (wc * 64 + n * 16) * 32 + laneoff);
    __builtin_amdgcn_s_setprio(1);
    #pragma unroll
    for (int m = 0; m < 4; ++m)
      #pragma unroll
      for (int n = 0; n < 4; ++n)
        acc[m][n] = __builtin_amdgcn_mfma_f32_16x16x32_bf16(af[m], bf[n], acc[m][n], 0, 0, 0);
    __builtin_amdgcn_s_setprio(0);
    if (kk + 2 < 16)      VMCNT(4);   // stage(kk+1) landed; stage(kk+2) in flight
    else if (kk + 1 < 16) VMCNT(0);
    __builtin_amdgcn_s_barrier();
  }

  // ---- epilogue: per-wave LDS slab (16 rows x 68 pitch), float4-coalesced IO ----
  float* slab = (float*)(&lds[0][0][0]) + w * (16 * 68);   // 4*16*68*4B = 17408B total
  const int row0 = tr * 128 + wr * 64, col0q = tc * 128 + wc * 64;
  const size_t xb = (size_t)b * CC * NN;
  const float* seb = se + (size_t)b * CC;
  #pragma unroll
  for (int m = 0; m < 4; ++m) {
    #pragma unroll
    for (int n = 0; n < 4; ++n)
      #pragma unroll
      for (int r = 0; r < 4; ++r)
        slab[(((l >> 4) << 2) + r) * 68 + n * 16 + (l & 15)] = acc[m][n][r];
    #pragma unroll
    for (int it = 0; it < 4; ++it) {
      const int rl = (it << 2) + (l >> 4);
      const int c  = row0 + m * 16 + rl;
      const int n4 = (l & 15) << 2;
      const float4 a = *(const float4*)&slab[rl * 68 + n4];
      const float sv = seb[c];
      const float om = 1.f - sv;
      const size_t go = xb + (size_t)c * NN + col0q + n4;
      const ushort4 hx = *(const ushort4*)(qhi + go);
      float4 o;
      o.x = sv * bf2f(hx.x) + om * a.x;
      o.y = sv * bf2f(hx.y) + om * a.y;
      o.z = sv * bf2f(hx.z) + om * a.z;
      o.w = sv * bf2f(hx.w) + om * a.w;
      *(float4*)(out + go) = o;
    }
  }
}

// ---------------------------------------------------------------------------------------
extern "C" void kernel_launch(void* const* d_in, const int* in_sizes, int n_in,
                              void* d_out, int out_size, void* d_ws, size_t ws_size,
                              hipStream_t stream) {
  (void)in_sizes; (void)n_in; (void)out_size;
  const float* x  = (const float*)d_in[0];
  const float* w1 = (const float*)d_in[1];
  const float* b1 = (const float*)d_in[2];
  const float* w2 = (const float*)d_in[3];
  const float* b2 = (const float*)d_in[4];
  float* out = (float*)d_out;

  const size_t O_QHI = 0;
  const size_t O_QLO = 67108864;
  const size_t O_QT  = 134217728;
  const size_t O_EP  = 201326592;
  const size_t EPSZ1 = 16777216;

  // need(KS) = O_EP + KS*EPSZ1 + att(8388608) + part(524288) + px/po/se(3*32768)
  const size_t TAIL = 8388608 + 524288 + 3 * 32768;      // 9,011,200
  const size_t NEED1 = O_EP + 1 * EPSZ1 + TAIL;          // 227,115,008
  const size_t NEED2 = O_EP + 2 * EPSZ1 + TAIL;          // 243,892,224
  const size_t NEED4 = O_EP + 4 * EPSZ1 + TAIL;          // 277,446,656

  if (ws_size < NEED1) return;   // fail loudly (output stays poisoned)
  const int ksplit = (ws_size >= NEED4) ? 4 : (ws_size >= NEED2) ? 2 : 1;

  char* ws = (char*)d_ws;
  unsigned short* qhi = (unsigned short*)(ws + O_QHI);
  unsigned short* qlo = (unsigned short*)(ws + O_QLO);
  unsigned short* qt  = (unsigned short*)(ws + O_QT);
  float*          EP  = (float*)(ws + O_EP);
  char* tail          = ws + O_EP + (size_t)ksplit * EPSZ1;
  unsigned short* att = (unsigned short*)(tail);
  float*          part= (float*)(tail + 8388608);
  float*          px  = (float*)(tail + 8912896);
  float*          po  = (float*)(tail + 8945664);
  float*          se  = (float*)(tail + 8978432);

  k_convert<<<dim3(16, 8, 16), 256, 0, stream>>>(x, qhi, qlo, qt, part);
  k_sumpart<<<32, 256, 0, stream>>>(part, px);
  if (ksplit == 4) {
    k_energy<4><<<640, 256, 0, stream>>>(qhi, qlo, EP);
    k_softmax<4><<<8192, 64, 0, stream>>>(EP, px, att, po);
  } else if (ksplit == 2) {
    k_energy<2><<<320, 256, 0, stream>>>(qhi, qlo, EP);
    k_softmax<2><<<8192, 64, 0, stream>>>(EP, px, att, po);
  } else {
    k_energy<1><<<160, 256, 0, stream>>>(qhi, qlo, EP);
    k_softmax<1><<<8192, 64, 0, stream>>>(EP, px, att, po);
  }
  k_mlp<<<16, 256, 0, stream>>>(px, po, w1, b1, w2, b2, se);
  k_out<<<2048, 256, 0, stream>>>(att, qt, se, qhi, out);
}

// Round 6
// 225.651 us; speedup vs baseline: 1.3994x; 1.3994x over previous
//
#include <hip/hip_runtime.h>
#include <cstdint>
#include <cstddef>

#define BB 16
#define CC 512
#define NN 4096

typedef __attribute__((ext_vector_type(4))) float f32x4;
typedef __attribute__((ext_vector_type(8))) _Float16 f16x8;

#define VMCNT(n) asm volatile("s_waitcnt vmcnt(" #n ")" ::: "memory")

__device__ __forceinline__ unsigned short f2h(float f) {
  _Float16 h = (_Float16)f;                       // v_cvt_f16_f32, RTN
  return __builtin_bit_cast(unsigned short, h);
}
__device__ __forceinline__ float h2f(unsigned short u) {
  return (float)__builtin_bit_cast(_Float16, u);
}

// async global->LDS, 16B per lane. LDS dest must be wave-uniform base; HW adds lane*16.
__device__ __forceinline__ void gload16(const unsigned short* g, short* l) {
  __builtin_amdgcn_global_load_lds(
      (const __attribute__((address_space(1))) unsigned int*)g,
      (__attribute__((address_space(3))) unsigned int*)(__attribute__((address_space(3))) short*)l,
      16, 0, 0);
}

// ---------------- Kernel A: x -> fp16 q, transposed q, row partial sums ---------------
__global__ __launch_bounds__(256) void k_convert(
    const float* __restrict__ x,
    unsigned short* __restrict__ qh,
    unsigned short* __restrict__ qt,
    float* __restrict__ part)
{
  const int nt = blockIdx.x;     // 16 tiles of 256 n
  const int ct = blockIdx.y;     // 8 tiles of 64 c
  const int b  = blockIdx.z;
  const int c0 = ct << 6;
  const int n0 = nt << 8;
  const int t  = threadIdx.x;
  const int w  = t >> 6;
  const int l  = t & 63;

  __shared__ unsigned short lt[256 * 65];   // [n_local][c_local], pitch 65 (bank spread)
  __shared__ float rsum[64];

  const size_t xb = (size_t)b * CC * NN;

  for (int i = 0; i < 16; ++i) {
    const int r = (i << 2) + w;                       // c row in tile (wave-uniform)
    const size_t off = xb + (size_t)(c0 + r) * NN + n0 + (l << 2);
    const float4 v = *(const float4*)(x + off);
    const unsigned short h0 = f2h(v.x), h1 = f2h(v.y), h2 = f2h(v.z), h3 = f2h(v.w);
    *(ushort4*)(qh + off) = make_ushort4(h0, h1, h2, h3);
    const int nl = l << 2;
    lt[(nl + 0) * 65 + r] = h0;
    lt[(nl + 1) * 65 + r] = h1;
    lt[(nl + 2) * 65 + r] = h2;
    lt[(nl + 3) * 65 + r] = h3;
    float s = v.x + v.y + v.z + v.w;
    #pragma unroll
    for (int o = 32; o > 0; o >>= 1) s += __shfl_down(s, o);
    if (l == 0) rsum[r] = s;                          // each wave owns distinct rows
  }
  __syncthreads();
  if (t < 64) part[((size_t)b * CC + c0 + t) * 16 + nt] = rsum[t];

  // transposed write: qt[b][n][c]
  #pragma unroll
  for (int p = 0; p < 8; ++p) {
    const int n   = (p << 5) + (t >> 3);
    const int cc8 = (t & 7) << 3;
    const unsigned short* e = &lt[n * 65 + cc8];
    uint4 pk;
    pk.x = (unsigned)e[0] | ((unsigned)e[1] << 16);
    pk.y = (unsigned)e[2] | ((unsigned)e[3] << 16);
    pk.z = (unsigned)e[4] | ((unsigned)e[5] << 16);
    pk.w = (unsigned)e[6] | ((unsigned)e[7] << 16);
    *(uint4*)(qt + ((size_t)b * NN + n0 + n) * CC + c0 + cc8) = pk;
  }
}

// ---------------- Kernel A2: sum row partials -> pooled_x raw sums --------------------
__global__ __launch_bounds__(256) void k_sumpart(const float* __restrict__ part,
                                                 float* __restrict__ px)
{
  const int g = blockIdx.x * 256 + threadIdx.x;   // 0..8191 = b*512+c
  float s = 0.f;
  #pragma unroll
  for (int i = 0; i < 16; ++i) s += part[(size_t)g * 16 + i];
  px[g] = s;
}

// ---------------- Kernel B: energy = q.qT, fp16 single-stream, SYMMETRIC upper-tri ----
// 128x128 tile, 4 waves, BK=32, 48 KiB LDS (3 blocks/CU). Depth-2 pipeline (3 bufs):
// VMCNT(4) before each barrier -> stage(kk+1) landed for all waves; stage(kk+2) stays
// in flight across the barrier (T4, sound cross-wave).
template <int KSPLIT>
__global__ __launch_bounds__(256, 3) void k_energy(
    const unsigned short* __restrict__ qh,
    float* __restrict__ EP)
{
  const int bx  = blockIdx.x;               // 160*KSPLIT blocks
  const int xcd = bx & 7;
  const int j   = bx >> 3;
  const int gi  = j / 10;
  const int t10 = j % 10;
  const int g   = xcd + (gi << 3);          // group = b*KSPLIT+ks, grouped per XCD
  const int b   = g / KSPLIT;
  const int ks  = g % KSPLIT;
  int tr, tc;
  if (t10 < 4)      { tr = 0; tc = t10; }
  else if (t10 < 7) { tr = 1; tc = t10 - 3; }
  else if (t10 < 9) { tr = 2; tc = t10 - 5; }
  else              { tr = 3; tc = 3; }
  const bool diag = (tr == tc);
  const int kbase = ks * (NN / KSPLIT);
  const int NK    = 128 / KSPLIT;           // K-steps of 32

  const int t = threadIdx.x, w = t >> 6, l = t & 63;
  const int wr = w >> 1, wc = w & 1;

  __shared__ short lds[3][2][128 * 32];     // [buf][A,B] = 48 KiB

  const size_t qoff = (size_t)b * CC * NN;
  const unsigned short* sA = qh + qoff + (size_t)(tr * 128) * NN;
  const unsigned short* sB = diag ? sA : qh + qoff + (size_t)(tc * 128) * NN;

  // staging: chunk = w*64+l; row = chunk>>2; stored kchunk = chunk&3;
  // logical kchunk = stored ^ ((row>>2)&3)  (XOR swizzle, pre-swizzled source)
  const int r1 = w * 16 + (l >> 2);
  const int kl = (((l & 3) ^ (l >> 4)) << 3);          // logical k elem offset
  const int d1 = w * 512;                               // LDS short offset (wave-uniform)
  const int d2 = 2048 + w * 512;

  // fragment read: row = base + (l&15); logical chunk = l>>4; stored = logical ^ ((row>>2)&3)
  const int laneoff = ((l & 15) << 5) + ((((l >> 4) ^ ((l >> 2) & 3))) << 3);

  f32x4 acc[4][4] = {};

  auto stage = [&](int buf, int kk) {       // always 4 loads (uniform vmcnt)
    const int k0 = kbase + kk * 32 + kl;
    gload16(sA + (size_t)r1 * NN + k0,        &lds[buf][0][d1]);
    gload16(sA + (size_t)(r1 + 64) * NN + k0, &lds[buf][0][d2]);
    gload16(sB + (size_t)r1 * NN + k0,        &lds[buf][1][d1]);
    gload16(sB + (size_t)(r1 + 64) * NN + k0, &lds[buf][1][d2]);
  };

  stage(0, 0);
  stage(1, 1);
  VMCNT(4);                                 // stage(0) landed (own wave)
  __builtin_amdgcn_s_barrier();             // -> stage(0) landed for ALL waves

  for (int kk = 0; kk < NK; ++kk) {
    const int cur = kk % 3;
    if (kk + 2 < NK) stage((kk + 2) % 3, kk + 2);   // buf read at kk-1 (barrier-protected)
    const short* A = &lds[cur][0][0];
    const short* Bm = &lds[cur][1][0];
    f16x8 ah[4], bh[4];
    #pragma unroll
    for (int m = 0; m < 4; ++m)
      ah[m] = *(const f16x8*)(A + (wr * 64 + m * 16) * 32 + laneoff);
    #pragma unroll
    for (int n = 0; n < 4; ++n)
      bh[n] = *(const f16x8*)(Bm + (wc * 64 + n * 16) * 32 + laneoff);
    __builtin_amdgcn_s_setprio(1);
    #pragma unroll
    for (int m = 0; m < 4; ++m)
      #pragma unroll
      for (int n = 0; n < 4; ++n)
        acc[m][n] = __builtin_amdgcn_mfma_f32_16x16x32_f16(ah[m], bh[n], acc[m][n], 0, 0, 0);
    __builtin_amdgcn_s_setprio(0);
    if (kk + 2 < NK)      VMCNT(4);   // stage(kk+1) landed; stage(kk+2) in flight
    else if (kk + 1 < NK) VMCNT(0);   // drain last prefetch
    __builtin_amdgcn_s_barrier();
  }

  const int row0 = tr * 128 + wr * 64, col0 = tc * 128 + wc * 64;
  float* Eb = EP + ((size_t)ks * BB + b) * CC * CC;
  #pragma unroll
  for (int m = 0; m < 4; ++m)
    #pragma unroll
    for (int n = 0; n < 4; ++n)
      #pragma unroll
      for (int r = 0; r < 4; ++r) {
        const int row = row0 + m * 16 + ((l >> 4) << 2) + r;   // C/D: row=(lane>>4)*4+reg
        const int col = col0 + n * 16 + (l & 15);              //      col=lane&15
        const float v = acc[m][n][r];
        Eb[(size_t)row * CC + col] = v;
        if (!diag) Eb[(size_t)col * CC + row] = v;   // mirror (L2 merges the scatter)
      }
}

// ---------------- Kernel C: att = softmax(-E) per row; pooled_out = att . mean_x ------
template <int NP>
__global__ __launch_bounds__(64) void k_softmax(
    const float* __restrict__ EP, const float* __restrict__ px,
    unsigned short* __restrict__ att, float* __restrict__ po)
{
  const int bx = blockIdx.x;                  // 8192 = b*512+c
  const int b = bx >> 9, c = bx & 511;
  const int l = threadIdx.x;
  const size_t rowoff = ((size_t)b * CC + c) * CC;
  const size_t PS = (size_t)BB * CC * CC;
  float v[8];
  float mn = 1e30f;
  #pragma unroll
  for (int i = 0; i < 8; ++i) {
    float s = EP[rowoff + l + i * 64];
    #pragma unroll
    for (int p = 1; p < NP; ++p) s += EP[p * PS + rowoff + l + i * 64];
    v[i] = s; mn = fminf(mn, s);
  }
  #pragma unroll
  for (int o = 32; o > 0; o >>= 1) mn = fminf(mn, __shfl_xor(mn, o));
  float s = 0.f;
  #pragma unroll
  for (int i = 0; i < 8; ++i) { v[i] = __expf(mn - v[i]); s += v[i]; }
  float dot = 0.f;
  const float* pxb = px + (size_t)b * CC;
  #pragma unroll
  for (int i = 0; i < 8; ++i) dot += v[i] * pxb[l + i * 64];
  #pragma unroll
  for (int o = 32; o > 0; o >>= 1) { s += __shfl_xor(s, o); dot += __shfl_xor(dot, o); }
  const float inv = 1.f / s;
  unsigned short* arow = att + ((size_t)b * CC + c) * CC;
  #pragma unroll
  for (int i = 0; i < 8; ++i) arow[l + i * 64] = f2h(v[i] * inv);
  if (l == 0) po[(size_t)b * CC + c] = dot / (s * 4096.f);
}

// ---------------- Kernel D: SE MLP -> se[b][c] -----------------------------------------
__global__ __launch_bounds__(256) void k_mlp(
    const float* __restrict__ px, const float* __restrict__ po,
    const float* __restrict__ w1, const float* __restrict__ b1,
    const float* __restrict__ w2, const float* __restrict__ b2,
    float* __restrict__ se)
{
  const int b = blockIdx.x, t = threadIdx.x;
  __shared__ float p[1024];
  __shared__ float hp[64][5];
  __shared__ float h[64];
  for (int i = t; i < 1024; i += 256)
    p[i] = (i < 512) ? px[(size_t)b * 512 + i] * (1.f / 4096.f)
                     : po[(size_t)b * 512 + i - 512];
  __syncthreads();
  {
    const int j = t >> 2, q = t & 3;
    float s = 0.f;
    const float* wr = w1 + (size_t)j * 1024 + q * 256;
    const float* pp = p + q * 256;
    for (int k = 0; k < 256; ++k) s += pp[k] * wr[k];
    hp[j][q] = s;
  }
  __syncthreads();
  if (t < 64) h[t] = fmaxf(hp[t][0] + hp[t][1] + hp[t][2] + hp[t][3] + b1[t], 0.f);
  __syncthreads();
  for (int c = t; c < 512; c += 256) {
    float s = b2[c];
    for (int j = 0; j < 64; ++j) s += h[j] * w2[(size_t)c * 64 + j];
    se[(size_t)b * 512 + c] = 1.f / (1.f + __expf(-s));
  }
}

// ---------------- Kernel E: out = att @ q, fused blend se*x + (1-se)*out --------------
// Depth-2 pipeline (3 buffers), VMCNT(4) before each barrier. Blend reads qh (fp16 x).
__global__ __launch_bounds__(256, 3) void k_out(
    const unsigned short* __restrict__ att,
    const unsigned short* __restrict__ qt,
    const float* __restrict__ se,
    const unsigned short* __restrict__ qh,
    float* __restrict__ out)
{
  const int bx = blockIdx.x;                      // 2048 blocks, XCD-grouped per batch
  const int xcd = bx & 7;
  const int j   = bx >> 3;                        // 0..255
  const int b   = xcd + ((j >> 7) << 3);          // 0..15, one batch's 128 tiles per XCD
  const int tt  = j & 127;
  const int tr = tt >> 5, tc = tt & 31;
  const int t = threadIdx.x, w = t >> 6, l = t & 63;
  const int wr = w >> 1, wc = w & 1;

  __shared__ short lds[3][2][128 * 32];           // 48 KiB (reused as epilogue slabs)

  const unsigned short* sA = att + (size_t)b * CC * CC + (size_t)(tr * 128) * CC;
  const unsigned short* sB = qt  + (size_t)b * NN * CC + (size_t)(tc * 128) * CC;

  const int r1 = w * 16 + (l >> 2);
  const int kl = (((l & 3) ^ (l >> 4)) << 3);
  const int d1 = w * 512, d2 = 2048 + w * 512;
  const int laneoff = ((l & 15) << 5) + ((((l >> 4) ^ ((l >> 2) & 3))) << 3);

  f32x4 acc[4][4] = {};

  auto stage = [&](int buf, int kk) {             // 4 loads
    const int k0 = kk * 32 + kl;
    gload16(sA + (size_t)r1 * CC + k0,        &lds[buf][0][d1]);
    gload16(sA + (size_t)(r1 + 64) * CC + k0, &lds[buf][0][d2]);
    gload16(sB + (size_t)r1 * CC + k0,        &lds[buf][1][d1]);
    gload16(sB + (size_t)(r1 + 64) * CC + k0, &lds[buf][1][d2]);
  };

  stage(0, 0);
  stage(1, 1);
  VMCNT(4);                                 // stage(0) landed (own wave)
  __builtin_amdgcn_s_barrier();             // -> landed for all waves

  for (int kk = 0; kk < 16; ++kk) {
    const int cur = kk % 3;
    if (kk + 2 < 16) stage((kk + 2) % 3, kk + 2);
    const short* A  = &lds[cur][0][0];
    const short* Bm = &lds[cur][1][0];
    f16x8 af[4], bf[4];
    #pragma unroll
    for (int m = 0; m < 4; ++m) af[m] = *(const f16x8*)(A  + (wr * 64 + m * 16) * 32 + laneoff);
    #pragma unroll
    for (int n = 0; n < 4; ++n) bf[n] = *(const f16x8*)(Bm + (wc * 64 + n * 16) * 32 + laneoff);
    __builtin_amdgcn_s_setprio(1);
    #pragma unroll
    for (int m = 0; m < 4; ++m)
      #pragma unroll
      for (int n = 0; n < 4; ++n)
        acc[m][n] = __builtin_amdgcn_mfma_f32_16x16x32_f16(af[m], bf[n], acc[m][n], 0, 0, 0);
    __builtin_amdgcn_s_setprio(0);
    if (kk + 2 < 16)      VMCNT(4);   // stage(kk+1) landed; stage(kk+2) in flight
    else if (kk + 1 < 16) VMCNT(0);
    __builtin_amdgcn_s_barrier();
  }

  // ---- epilogue: per-wave LDS slab (16 rows x 68 pitch), float4-coalesced IO ----
  float* slab = (float*)(&lds[0][0][0]) + w * (16 * 68);   // 4*16*68*4B = 17408B total
  const int row0 = tr * 128 + wr * 64, col0q = tc * 128 + wc * 64;
  const size_t xb = (size_t)b * CC * NN;
  const float* seb = se + (size_t)b * CC;
  #pragma unroll
  for (int m = 0; m < 4; ++m) {
    #pragma unroll
    for (int n = 0; n < 4; ++n)
      #pragma unroll
      for (int r = 0; r < 4; ++r)
        slab[(((l >> 4) << 2) + r) * 68 + n * 16 + (l & 15)] = acc[m][n][r];
    #pragma unroll
    for (int it = 0; it < 4; ++it) {
      const int rl = (it << 2) + (l >> 4);
      const int c  = row0 + m * 16 + rl;
      const int n4 = (l & 15) << 2;
      const float4 a = *(const float4*)&slab[rl * 68 + n4];
      const float sv = seb[c];
      const float om = 1.f - sv;
      const size_t go = xb + (size_t)c * NN + col0q + n4;
      const ushort4 hx = *(const ushort4*)(qh + go);
      float4 o;
      o.x = sv * h2f(hx.x) + om * a.x;
      o.y = sv * h2f(hx.y) + om * a.y;
      o.z = sv * h2f(hx.z) + om * a.z;
      o.w = sv * h2f(hx.w) + om * a.w;
      *(float4*)(out + go) = o;
    }
  }
}

// ---------------------------------------------------------------------------------------
extern "C" void kernel_launch(void* const* d_in, const int* in_sizes, int n_in,
                              void* d_out, int out_size, void* d_ws, size_t ws_size,
                              hipStream_t stream) {
  (void)in_sizes; (void)n_in; (void)out_size;
  const float* x  = (const float*)d_in[0];
  const float* w1 = (const float*)d_in[1];
  const float* b1 = (const float*)d_in[2];
  const float* w2 = (const float*)d_in[3];
  const float* b2 = (const float*)d_in[4];
  float* out = (float*)d_out;

  const size_t O_QH  = 0;                       // 67,108,864 (fp16 q)
  const size_t O_QT  = 67108864;                // 67,108,864 (fp16 qT)
  const size_t O_EP  = 134217728;               // KSPLIT x 16,777,216 (fp32 E partials)
  const size_t EPSZ1 = 16777216;

  const size_t TAIL = 8388608 + 524288 + 3 * 32768;      // att + part + px/po/se
  const size_t NEED1 = O_EP + 1 * EPSZ1 + TAIL;          // 160,006,144
  const size_t NEED2 = O_EP + 2 * EPSZ1 + TAIL;          // 176,783,360
  const size_t NEED4 = O_EP + 4 * EPSZ1 + TAIL;          // 210,337,792

  if (ws_size < NEED1) return;   // fail loudly (output stays poisoned)
  const int ksplit = (ws_size >= NEED4) ? 4 : (ws_size >= NEED2) ? 2 : 1;

  char* ws = (char*)d_ws;
  unsigned short* qh  = (unsigned short*)(ws + O_QH);
  unsigned short* qt  = (unsigned short*)(ws + O_QT);
  float*          EP  = (float*)(ws + O_EP);
  char* tail          = ws + O_EP + (size_t)ksplit * EPSZ1;
  unsigned short* att = (unsigned short*)(tail);
  float*          part= (float*)(tail + 8388608);
  float*          px  = (float*)(tail + 8912896);
  float*          po  = (float*)(tail + 8945664);
  float*          se  = (float*)(tail + 8978432);

  k_convert<<<dim3(16, 8, 16), 256, 0, stream>>>(x, qh, qt, part);
  k_sumpart<<<32, 256, 0, stream>>>(part, px);
  if (ksplit == 4) {
    k_energy<4><<<640, 256, 0, stream>>>(qh, EP);
    k_softmax<4><<<8192, 64, 0, stream>>>(EP, px, att, po);
  } else if (ksplit == 2) {
    k_energy<2><<<320, 256, 0, stream>>>(qh, EP);
    k_softmax<2><<<8192, 64, 0, stream>>>(EP, px, att, po);
  } else {
    k_energy<1><<<160, 256, 0, stream>>>(qh, EP);
    k_softmax<1><<<8192, 64, 0, stream>>>(EP, px, att, po);
  }
  k_mlp<<<16, 256, 0, stream>>>(px, po, w1, b1, w2, b2, se);
  k_out<<<2048, 256, 0, stream>>>(att, qt, se, qh, out);
}

// Round 7
// 219.355 us; speedup vs baseline: 1.4396x; 1.0287x over previous
//
#include <hip/hip_runtime.h>
#include <cstdint>
#include <cstddef>

#define BB 16
#define CC 512
#define NN 4096

typedef __attribute__((ext_vector_type(4))) float f32x4;
typedef __attribute__((ext_vector_type(8))) _Float16 f16x8;

#define VMCNT(n) asm volatile("s_waitcnt vmcnt(" #n ")" ::: "memory")

__device__ __forceinline__ unsigned short f2h(float f) {
  _Float16 h = (_Float16)f;                       // v_cvt_f16_f32, RTN
  return __builtin_bit_cast(unsigned short, h);
}
__device__ __forceinline__ float h2f(unsigned short u) {
  return (float)__builtin_bit_cast(_Float16, u);
}

// async global->LDS, 16B per lane. LDS dest must be wave-uniform base; HW adds lane*16.
__device__ __forceinline__ void gload16(const unsigned short* g, short* l) {
  __builtin_amdgcn_global_load_lds(
      (const __attribute__((address_space(1))) unsigned int*)g,
      (__attribute__((address_space(3))) unsigned int*)(__attribute__((address_space(3))) short*)l,
      16, 0, 0);
}

// ---------------- Kernel A: x -> fp16 q, transposed q, row partial sums ---------------
__global__ __launch_bounds__(256) void k_convert(
    const float* __restrict__ x,
    unsigned short* __restrict__ qh,
    unsigned short* __restrict__ qt,
    float* __restrict__ part)
{
  const int nt = blockIdx.x;     // 16 tiles of 256 n
  const int ct = blockIdx.y;     // 8 tiles of 64 c
  const int b  = blockIdx.z;
  const int c0 = ct << 6;
  const int n0 = nt << 8;
  const int t  = threadIdx.x;
  const int w  = t >> 6;
  const int l  = t & 63;

  __shared__ unsigned short lt[256 * 65];   // [n_local][c_local], pitch 65 (bank spread)
  __shared__ float rsum[64];

  const size_t xb = (size_t)b * CC * NN;

  for (int i = 0; i < 16; ++i) {
    const int r = (i << 2) + w;                       // c row in tile (wave-uniform)
    const size_t off = xb + (size_t)(c0 + r) * NN + n0 + (l << 2);
    const float4 v = *(const float4*)(x + off);
    const unsigned short h0 = f2h(v.x), h1 = f2h(v.y), h2 = f2h(v.z), h3 = f2h(v.w);
    *(ushort4*)(qh + off) = make_ushort4(h0, h1, h2, h3);
    const int nl = l << 2;
    lt[(nl + 0) * 65 + r] = h0;
    lt[(nl + 1) * 65 + r] = h1;
    lt[(nl + 2) * 65 + r] = h2;
    lt[(nl + 3) * 65 + r] = h3;
    float s = v.x + v.y + v.z + v.w;
    #pragma unroll
    for (int o = 32; o > 0; o >>= 1) s += __shfl_down(s, o);
    if (l == 0) rsum[r] = s;                          // each wave owns distinct rows
  }
  __syncthreads();
  if (t < 64) part[((size_t)b * CC + c0 + t) * 16 + nt] = rsum[t];

  // transposed write: qt[b][n][c]
  #pragma unroll
  for (int p = 0; p < 8; ++p) {
    const int n   = (p << 5) + (t >> 3);
    const int cc8 = (t & 7) << 3;
    const unsigned short* e = &lt[n * 65 + cc8];
    uint4 pk;
    pk.x = (unsigned)e[0] | ((unsigned)e[1] << 16);
    pk.y = (unsigned)e[2] | ((unsigned)e[3] << 16);
    pk.z = (unsigned)e[4] | ((unsigned)e[5] << 16);
    pk.w = (unsigned)e[6] | ((unsigned)e[7] << 16);
    *(uint4*)(qt + ((size_t)b * NN + n0 + n) * CC + c0 + cc8) = pk;
  }
}

// ---------------- Kernel A2: sum row partials -> pooled_x raw sums --------------------
__global__ __launch_bounds__(256) void k_sumpart(const float* __restrict__ part,
                                                 float* __restrict__ px)
{
  const int g = blockIdx.x * 256 + threadIdx.x;   // 0..8191 = b*512+c
  float s = 0.f;
  #pragma unroll
  for (int i = 0; i < 16; ++i) s += part[(size_t)g * 16 + i];
  px[g] = s;
}

// ---------------- Kernel B: energy = q.qT, fp16 single-stream, SYMMETRIC upper-tri ----
// 128x128 tile, 4 waves, BK=32, 48 KiB LDS (3 blocks/CU). Depth-2 pipeline (3 bufs):
// VMCNT(4) before each barrier -> stage(kk+1) landed for all waves; stage(kk+2) stays
// in flight across the barrier (T4, sound cross-wave).
template <int KSPLIT>
__global__ __launch_bounds__(256, 3) void k_energy(
    const unsigned short* __restrict__ qh,
    float* __restrict__ EP)
{
  const int bx  = blockIdx.x;               // 160*KSPLIT blocks
  const int xcd = bx & 7;
  const int j   = bx >> 3;
  const int gi  = j / 10;
  const int t10 = j % 10;
  const int g   = xcd + (gi << 3);          // group = b*KSPLIT+ks, grouped per XCD
  const int b   = g / KSPLIT;
  const int ks  = g % KSPLIT;
  int tr, tc;
  if (t10 < 4)      { tr = 0; tc = t10; }
  else if (t10 < 7) { tr = 1; tc = t10 - 3; }
  else if (t10 < 9) { tr = 2; tc = t10 - 5; }
  else              { tr = 3; tc = 3; }
  const bool diag = (tr == tc);
  const int kbase = ks * (NN / KSPLIT);
  const int NK    = 128 / KSPLIT;           // K-steps of 32

  const int t = threadIdx.x, w = t >> 6, l = t & 63;
  const int wr = w >> 1, wc = w & 1;

  __shared__ short lds[3][2][128 * 32];     // [buf][A,B] = 48 KiB

  const size_t qoff = (size_t)b * CC * NN;
  const unsigned short* sA = qh + qoff + (size_t)(tr * 128) * NN;
  const unsigned short* sB = diag ? sA : qh + qoff + (size_t)(tc * 128) * NN;

  // staging: chunk = w*64+l; row = chunk>>2; stored kchunk = chunk&3;
  // logical kchunk = stored ^ ((row>>2)&3)  (XOR swizzle, pre-swizzled source)
  const int r1 = w * 16 + (l >> 2);
  const int kl = (((l & 3) ^ (l >> 4)) << 3);          // logical k elem offset
  const int d1 = w * 512;                               // LDS short offset (wave-uniform)
  const int d2 = 2048 + w * 512;

  // fragment read: row = base + (l&15); logical chunk = l>>4; stored = logical ^ ((row>>2)&3)
  const int laneoff = ((l & 15) << 5) + ((((l >> 4) ^ ((l >> 2) & 3))) << 3);

  f32x4 acc[4][4] = {};

  auto stage = [&](int buf, int kk) {       // always 4 loads (uniform vmcnt)
    const int k0 = kbase + kk * 32 + kl;
    gload16(sA + (size_t)r1 * NN + k0,        &lds[buf][0][d1]);
    gload16(sA + (size_t)(r1 + 64) * NN + k0, &lds[buf][0][d2]);
    gload16(sB + (size_t)r1 * NN + k0,        &lds[buf][1][d1]);
    gload16(sB + (size_t)(r1 + 64) * NN + k0, &lds[buf][1][d2]);
  };

  stage(0, 0);
  stage(1, 1);
  VMCNT(4);                                 // stage(0) landed (own wave)
  __builtin_amdgcn_s_barrier();             // -> stage(0) landed for ALL waves

  for (int kk = 0; kk < NK; ++kk) {
    const int cur = kk % 3;
    if (kk + 2 < NK) stage((kk + 2) % 3, kk + 2);   // buf read at kk-1 (barrier-protected)
    const short* A = &lds[cur][0][0];
    const short* Bm = &lds[cur][1][0];
    f16x8 ah[4], bh[4];
    #pragma unroll
    for (int m = 0; m < 4; ++m)
      ah[m] = *(const f16x8*)(A + (wr * 64 + m * 16) * 32 + laneoff);
    #pragma unroll
    for (int n = 0; n < 4; ++n)
      bh[n] = *(const f16x8*)(Bm + (wc * 64 + n * 16) * 32 + laneoff);
    __builtin_amdgcn_s_setprio(1);
    #pragma unroll
    for (int m = 0; m < 4; ++m)
      #pragma unroll
      for (int n = 0; n < 4; ++n)
        acc[m][n] = __builtin_amdgcn_mfma_f32_16x16x32_f16(ah[m], bh[n], acc[m][n], 0, 0, 0);
    __builtin_amdgcn_s_setprio(0);
    if (kk + 2 < NK)      VMCNT(4);   // stage(kk+1) landed; stage(kk+2) in flight
    else if (kk + 1 < NK) VMCNT(0);   // drain last prefetch
    __builtin_amdgcn_s_barrier();
  }

  const int row0 = tr * 128 + wr * 64, col0 = tc * 128 + wc * 64;
  float* Eb = EP + ((size_t)ks * BB + b) * CC * CC;
  #pragma unroll
  for (int m = 0; m < 4; ++m)
    #pragma unroll
    for (int n = 0; n < 4; ++n)
      #pragma unroll
      for (int r = 0; r < 4; ++r) {
        const int row = row0 + m * 16 + ((l >> 4) << 2) + r;   // C/D: row=(lane>>4)*4+reg
        const int col = col0 + n * 16 + (l & 15);              //      col=lane&15
        const float v = acc[m][n][r];
        Eb[(size_t)row * CC + col] = v;
        if (!diag) Eb[(size_t)col * CC + row] = v;   // mirror (L2 merges the scatter)
      }
}

// ---------------- Kernel C: att = softmax(-E) per row; pooled_out = att . mean_x ------
template <int NP>
__global__ __launch_bounds__(64) void k_softmax(
    const float* __restrict__ EP, const float* __restrict__ px,
    unsigned short* __restrict__ att, float* __restrict__ po)
{
  const int bx = blockIdx.x;                  // 8192 = b*512+c
  const int b = bx >> 9, c = bx & 511;
  const int l = threadIdx.x;
  const size_t rowoff = ((size_t)b * CC + c) * CC;
  const size_t PS = (size_t)BB * CC * CC;
  float v[8];
  float mn = 1e30f;
  #pragma unroll
  for (int i = 0; i < 8; ++i) {
    float s = EP[rowoff + l + i * 64];
    #pragma unroll
    for (int p = 1; p < NP; ++p) s += EP[p * PS + rowoff + l + i * 64];
    v[i] = s; mn = fminf(mn, s);
  }
  #pragma unroll
  for (int o = 32; o > 0; o >>= 1) mn = fminf(mn, __shfl_xor(mn, o));
  float s = 0.f;
  #pragma unroll
  for (int i = 0; i < 8; ++i) { v[i] = __expf(mn - v[i]); s += v[i]; }
  float dot = 0.f;
  const float* pxb = px + (size_t)b * CC;
  #pragma unroll
  for (int i = 0; i < 8; ++i) dot += v[i] * pxb[l + i * 64];
  #pragma unroll
  for (int o = 32; o > 0; o >>= 1) { s += __shfl_xor(s, o); dot += __shfl_xor(dot, o); }
  const float inv = 1.f / s;
  unsigned short* arow = att + ((size_t)b * CC + c) * CC;
  #pragma unroll
  for (int i = 0; i < 8; ++i) arow[l + i * 64] = f2h(v[i] * inv);
  if (l == 0) po[(size_t)b * CC + c] = dot / (s * 4096.f);
}

// ---------------- Kernel D: SE MLP -> se[b][c] -----------------------------------------
__global__ __launch_bounds__(256) void k_mlp(
    const float* __restrict__ px, const float* __restrict__ po,
    const float* __restrict__ w1, const float* __restrict__ b1,
    const float* __restrict__ w2, const float* __restrict__ b2,
    float* __restrict__ se)
{
  const int b = blockIdx.x, t = threadIdx.x;
  __shared__ float p[1024];
  __shared__ float hp[64][5];
  __shared__ float h[64];
  for (int i = t; i < 1024; i += 256)
    p[i] = (i < 512) ? px[(size_t)b * 512 + i] * (1.f / 4096.f)
                     : po[(size_t)b * 512 + i - 512];
  __syncthreads();
  {
    const int j = t >> 2, q = t & 3;
    float s = 0.f;
    const float* wr = w1 + (size_t)j * 1024 + q * 256;
    const float* pp = p + q * 256;
    for (int k = 0; k < 256; ++k) s += pp[k] * wr[k];
    hp[j][q] = s;
  }
  __syncthreads();
  if (t < 64) h[t] = fmaxf(hp[t][0] + hp[t][1] + hp[t][2] + hp[t][3] + b1[t], 0.f);
  __syncthreads();
  for (int c = t; c < 512; c += 256) {
    float s = b2[c];
    for (int j = 0; j < 64; ++j) s += h[j] * w2[(size_t)c * 64 + j];
    se[(size_t)b * 512 + c] = 1.f / (1.f + __expf(-s));
  }
}

// ---------------- Kernel E: out = att @ q, fused blend se*x + (1-se)*out --------------
// 8-wave (512t) 128x256 tile, 1024 blocks, LDS 3x24KB=72KB -> 2 blocks/CU = 16 waves/CU.
// Depth-2 pipeline: 3 gload16/wave/stage; VMCNT(3) before each barrier. Blend reads qh.
__global__ __launch_bounds__(512, 4) void k_out(
    const unsigned short* __restrict__ att,
    const unsigned short* __restrict__ qt,
    const float* __restrict__ se,
    const unsigned short* __restrict__ qh,
    float* __restrict__ out)
{
  const int bx = blockIdx.x;                      // 1024 blocks, XCD-grouped per batch
  const int xcd = bx & 7;
  const int j   = bx >> 3;                        // 0..127
  const int b   = xcd + ((j >> 6) << 3);          // 2 batches per XCD
  const int tt  = j & 63;
  const int tr = tt >> 4, tc = tt & 15;           // tr: 4 x 128 c-rows; tc: 16 x 256 n
  const int t = threadIdx.x, w = t >> 6, l = t & 63;
  const int wr = w >> 2, wc = w & 3;              // wave quadrant: 2 x 4 of 64x64

  // [buf][ A:128x32 | B:256x32 ] halves; 12288 halves = 24 KiB per buf
  __shared__ short lds[3][12288];

  const unsigned short* sA = att + (size_t)b * CC * CC + (size_t)(tr * 128) * CC;
  const unsigned short* sB = qt  + (size_t)b * NN * CC + (size_t)(tc * 256) * CC;

  const int r1 = w * 16 + (l >> 2);               // staged row (A: [0,128); B: +0/+128)
  const int kl = (((l & 3) ^ (l >> 4)) << 3);     // pre-swizzled source k offset
  const int dA  = w * 512;                        // wave-uniform LDS half-offsets
  const int dB0 = 4096 + w * 512;
  const int dB1 = 8192 + w * 512;
  const int laneoff = ((l & 15) << 5) + ((((l >> 4) ^ ((l >> 2) & 3))) << 3);

  f32x4 acc[4][4] = {};

  auto stage = [&](int buf, int kk) {             // 3 loads per wave (uniform vmcnt)
    const int k0 = kk * 32 + kl;
    gload16(sA + (size_t)r1 * CC + k0,         &lds[buf][dA]);
    gload16(sB + (size_t)r1 * CC + k0,         &lds[buf][dB0]);
    gload16(sB + (size_t)(r1 + 128) * CC + k0, &lds[buf][dB1]);
  };

  stage(0, 0);
  stage(1, 1);
  VMCNT(3);                                 // stage(0) landed (own wave)
  __builtin_amdgcn_s_barrier();             // -> landed for all waves

  for (int kk = 0; kk < 16; ++kk) {
    const int cur = kk % 3;
    if (kk + 2 < 16) stage((kk + 2) % 3, kk + 2);
    const short* A  = &lds[cur][0];
    const short* Bm = &lds[cur][4096];
    f16x8 af[4], bf[4];
    #pragma unroll
    for (int m = 0; m < 4; ++m) af[m] = *(const f16x8*)(A  + (wr * 64 + m * 16) * 32 + laneoff);
    #pragma unroll
    for (int n = 0; n < 4; ++n) bf[n] = *(const f16x8*)(Bm + (wc * 64 + n * 16) * 32 + laneoff);
    __builtin_amdgcn_s_setprio(1);
    #pragma unroll
    for (int m = 0; m < 4; ++m)
      #pragma unroll
      for (int n = 0; n < 4; ++n)
        acc[m][n] = __builtin_amdgcn_mfma_f32_16x16x32_f16(af[m], bf[n], acc[m][n], 0, 0, 0);
    __builtin_amdgcn_s_setprio(0);
    if (kk + 2 < 16)      VMCNT(3);   // stage(kk+1) landed; stage(kk+2) in flight
    else if (kk + 1 < 16) VMCNT(0);
    __builtin_amdgcn_s_barrier();
  }

  // ---- epilogue: per-wave LDS slab (16 rows x 68 pitch), float4-coalesced IO ----
  float* slab = (float*)(&lds[0][0]) + w * (16 * 68);   // 8 x 4352 B = 34.8 KB <= 72 KB
  const int row0 = tr * 128 + wr * 64, col0q = tc * 256 + wc * 64;
  const size_t xb = (size_t)b * CC * NN;
  const float* seb = se + (size_t)b * CC;
  #pragma unroll
  for (int m = 0; m < 4; ++m) {
    #pragma unroll
    for (int n = 0; n < 4; ++n)
      #pragma unroll
      for (int r = 0; r < 4; ++r)
        slab[(((l >> 4) << 2) + r) * 68 + n * 16 + (l & 15)] = acc[m][n][r];
    #pragma unroll
    for (int it = 0; it < 4; ++it) {
      const int rl = (it << 2) + (l >> 4);
      const int c  = row0 + m * 16 + rl;
      const int n4 = (l & 15) << 2;
      const float4 a = *(const float4*)&slab[rl * 68 + n4];
      const float sv = seb[c];
      const float om = 1.f - sv;
      const size_t go = xb + (size_t)c * NN + col0q + n4;
      const ushort4 hx = *(const ushort4*)(qh + go);
      float4 o;
      o.x = sv * h2f(hx.x) + om * a.x;
      o.y = sv * h2f(hx.y) + om * a.y;
      o.z = sv * h2f(hx.z) + om * a.z;
      o.w = sv * h2f(hx.w) + om * a.w;
      *(float4*)(out + go) = o;
    }
  }
}

// ---------------------------------------------------------------------------------------
extern "C" void kernel_launch(void* const* d_in, const int* in_sizes, int n_in,
                              void* d_out, int out_size, void* d_ws, size_t ws_size,
                              hipStream_t stream) {
  (void)in_sizes; (void)n_in; (void)out_size;
  const float* x  = (const float*)d_in[0];
  const float* w1 = (const float*)d_in[1];
  const float* b1 = (const float*)d_in[2];
  const float* w2 = (const float*)d_in[3];
  const float* b2 = (const float*)d_in[4];
  float* out = (float*)d_out;

  const size_t O_QH  = 0;                       // 67,108,864 (fp16 q)
  const size_t O_QT  = 67108864;                // 67,108,864 (fp16 qT)
  const size_t O_EP  = 134217728;               // KSPLIT x 16,777,216 (fp32 E partials)
  const size_t EPSZ1 = 16777216;

  const size_t TAIL = 8388608 + 524288 + 3 * 32768;      // att + part + px/po/se
  const size_t NEED1 = O_EP + 1 * EPSZ1 + TAIL;          // 160,006,144
  const size_t NEED2 = O_EP + 2 * EPSZ1 + TAIL;          // 176,783,360
  const size_t NEED4 = O_EP + 4 * EPSZ1 + TAIL;          // 210,337,792

  if (ws_size < NEED1) return;   // fail loudly (output stays poisoned)
  const int ksplit = (ws_size >= NEED4) ? 4 : (ws_size >= NEED2) ? 2 : 1;

  char* ws = (char*)d_ws;
  unsigned short* qh  = (unsigned short*)(ws + O_QH);
  unsigned short* qt  = (unsigned short*)(ws + O_QT);
  float*          EP  = (float*)(ws + O_EP);
  char* tail          = ws + O_EP + (size_t)ksplit * EPSZ1;
  unsigned short* att = (unsigned short*)(tail);
  float*          part= (float*)(tail + 8388608);
  float*          px  = (float*)(tail + 8912896);
  float*          po  = (float*)(tail + 8945664);
  float*          se  = (float*)(tail + 8978432);

  k_convert<<<dim3(16, 8, 16), 256, 0, stream>>>(x, qh, qt, part);
  k_sumpart<<<32, 256, 0, stream>>>(part, px);
  if (ksplit == 4) {
    k_energy<4><<<640, 256, 0, stream>>>(qh, EP);
    k_softmax<4><<<8192, 64, 0, stream>>>(EP, px, att, po);
  } else if (ksplit == 2) {
    k_energy<2><<<320, 256, 0, stream>>>(qh, EP);
    k_softmax<2><<<8192, 64, 0, stream>>>(EP, px, att, po);
  } else {
    k_energy<1><<<160, 256, 0, stream>>>(qh, EP);
    k_softmax<1><<<8192, 64, 0, stream>>>(EP, px, att, po);
  }
  k_mlp<<<16, 256, 0, stream>>>(px, po, w1, b1, w2, b2, se);
  k_out<<<1024, 512, 0, stream>>>(att, qt, se, qh, out);
}

// Round 8
// 217.165 us; speedup vs baseline: 1.4541x; 1.0101x over previous
//
#include <hip/hip_runtime.h>
#include <cstdint>
#include <cstddef>

#define BB 16
#define CC 512
#define NN 4096

typedef __attribute__((ext_vector_type(4))) float f32x4;
typedef __attribute__((ext_vector_type(8))) _Float16 f16x8;

#define VMCNT(n) asm volatile("s_waitcnt vmcnt(" #n ")" ::: "memory")

__device__ __forceinline__ unsigned short f2h(float f) {
  _Float16 h = (_Float16)f;                       // v_cvt_f16_f32, RTN
  return __builtin_bit_cast(unsigned short, h);
}
__device__ __forceinline__ float h2f(unsigned short u) {
  return (float)__builtin_bit_cast(_Float16, u);
}

// async global->LDS, 16B per lane. LDS dest must be wave-uniform base; HW adds lane*16.
__device__ __forceinline__ void gload16(const unsigned short* g, short* l) {
  __builtin_amdgcn_global_load_lds(
      (const __attribute__((address_space(1))) unsigned int*)g,
      (__attribute__((address_space(3))) unsigned int*)(__attribute__((address_space(3))) short*)l,
      16, 0, 0);
}

// ---------------- Kernel A: x -> fp16 q, transposed q, row partial sums ---------------
// 4096 blocks (32 n-tiles x 8 c-tiles x 16 b), ~19 KB LDS -> 8 blocks/CU = 32 waves/CU.
// Row-sum via 2-shfl quad-reduce -> fs[64][8] -> 64-thread final pass (no 6-shfl chain).
__global__ __launch_bounds__(256) void k_convert(
    const float* __restrict__ x,
    unsigned short* __restrict__ qh,
    unsigned short* __restrict__ qt,
    float* __restrict__ part)
{
  const int nt = blockIdx.x;     // 32 tiles of 128 n
  const int ct = blockIdx.y;     // 8 tiles of 64 c
  const int b  = blockIdx.z;
  const int c0 = ct << 6;
  const int n0 = nt << 7;
  const int t  = threadIdx.x;
  const int w  = t >> 6;
  const int l  = t & 63;

  __shared__ unsigned short lt[128 * 65];   // [n_local][c_local], pitch 65 (bank spread)
  __shared__ float fs[64][8];               // per-row quad partials

  const size_t xb = (size_t)b * CC * NN;

  for (int i = 0; i < 8; ++i) {
    const int r  = (i << 3) + (w << 1) + (l >> 5);    // c row in tile (2 rows/wave)
    const int nl = (l & 31) << 2;                     // n offset in tile [0,128)
    const size_t off = xb + (size_t)(c0 + r) * NN + n0 + nl;
    const float4 v = *(const float4*)(x + off);
    const unsigned short h0 = f2h(v.x), h1 = f2h(v.y), h2 = f2h(v.z), h3 = f2h(v.w);
    *(ushort4*)(qh + off) = make_ushort4(h0, h1, h2, h3);
    lt[(nl + 0) * 65 + r] = h0;
    lt[(nl + 1) * 65 + r] = h1;
    lt[(nl + 2) * 65 + r] = h2;
    lt[(nl + 3) * 65 + r] = h3;
    float s = v.x + v.y + v.z + v.w;
    s += __shfl_xor(s, 1);
    s += __shfl_xor(s, 2);                            // quad sum (all same row)
    if ((l & 3) == 0) fs[r][(l & 31) >> 2] = s;
  }
  __syncthreads();
  if (t < 64) {
    float s = 0.f;
    #pragma unroll
    for (int qd = 0; qd < 8; ++qd) s += fs[t][qd];
    part[((size_t)b * CC + c0 + t) * 32 + nt] = s;
  }

  // transposed write: qt[b][n][c]
  #pragma unroll
  for (int p = 0; p < 4; ++p) {
    const int n   = (p << 5) + (t >> 3);
    const int cc8 = (t & 7) << 3;
    const unsigned short* e = &lt[n * 65 + cc8];
    uint4 pk;
    pk.x = (unsigned)e[0] | ((unsigned)e[1] << 16);
    pk.y = (unsigned)e[2] | ((unsigned)e[3] << 16);
    pk.z = (unsigned)e[4] | ((unsigned)e[5] << 16);
    pk.w = (unsigned)e[6] | ((unsigned)e[7] << 16);
    *(uint4*)(qt + ((size_t)b * NN + n0 + n) * CC + c0 + cc8) = pk;
  }
}

// ---------------- Kernel A2: sum row partials -> pooled_x raw sums --------------------
__global__ __launch_bounds__(256) void k_sumpart(const float* __restrict__ part,
                                                 float* __restrict__ px)
{
  const int g = blockIdx.x * 256 + threadIdx.x;   // 0..8191 = b*512+c
  float s = 0.f;
  #pragma unroll
  for (int i = 0; i < 32; ++i) s += part[(size_t)g * 32 + i];
  px[g] = s;
}

// ---------------- Kernel B: energy = q.qT, fp16 single-stream, SYMMETRIC upper-tri ----
// 128x128 tile, 4 waves, BK=32, 48 KiB LDS (3 blocks/CU). Depth-2 pipeline (3 bufs):
// VMCNT(4) before each barrier -> stage(kk+1) landed for all waves; stage(kk+2) stays
// in flight across the barrier (T4, sound cross-wave).
template <int KSPLIT>
__global__ __launch_bounds__(256, 3) void k_energy(
    const unsigned short* __restrict__ qh,
    float* __restrict__ EP)
{
  const int bx  = blockIdx.x;               // 160*KSPLIT blocks
  const int xcd = bx & 7;
  const int j   = bx >> 3;
  const int gi  = j / 10;
  const int t10 = j % 10;
  const int g   = xcd + (gi << 3);          // group = b*KSPLIT+ks, grouped per XCD
  const int b   = g / KSPLIT;
  const int ks  = g % KSPLIT;
  int tr, tc;
  if (t10 < 4)      { tr = 0; tc = t10; }
  else if (t10 < 7) { tr = 1; tc = t10 - 3; }
  else if (t10 < 9) { tr = 2; tc = t10 - 5; }
  else              { tr = 3; tc = 3; }
  const bool diag = (tr == tc);
  const int kbase = ks * (NN / KSPLIT);
  const int NK    = 128 / KSPLIT;           // K-steps of 32

  const int t = threadIdx.x, w = t >> 6, l = t & 63;
  const int wr = w >> 1, wc = w & 1;

  __shared__ short lds[3][2][128 * 32];     // [buf][A,B] = 48 KiB

  const size_t qoff = (size_t)b * CC * NN;
  const unsigned short* sA = qh + qoff + (size_t)(tr * 128) * NN;
  const unsigned short* sB = diag ? sA : qh + qoff + (size_t)(tc * 128) * NN;

  // staging: chunk = w*64+l; row = chunk>>2; stored kchunk = chunk&3;
  // logical kchunk = stored ^ ((row>>2)&3)  (XOR swizzle, pre-swizzled source)
  const int r1 = w * 16 + (l >> 2);
  const int kl = (((l & 3) ^ (l >> 4)) << 3);          // logical k elem offset
  const int d1 = w * 512;                               // LDS short offset (wave-uniform)
  const int d2 = 2048 + w * 512;

  // fragment read: row = base + (l&15); logical chunk = l>>4; stored = logical ^ ((row>>2)&3)
  const int laneoff = ((l & 15) << 5) + ((((l >> 4) ^ ((l >> 2) & 3))) << 3);

  f32x4 acc[4][4] = {};

  auto stage = [&](int buf, int kk) {       // always 4 loads (uniform vmcnt)
    const int k0 = kbase + kk * 32 + kl;
    gload16(sA + (size_t)r1 * NN + k0,        &lds[buf][0][d1]);
    gload16(sA + (size_t)(r1 + 64) * NN + k0, &lds[buf][0][d2]);
    gload16(sB + (size_t)r1 * NN + k0,        &lds[buf][1][d1]);
    gload16(sB + (size_t)(r1 + 64) * NN + k0, &lds[buf][1][d2]);
  };

  stage(0, 0);
  stage(1, 1);
  VMCNT(4);                                 // stage(0) landed (own wave)
  __builtin_amdgcn_s_barrier();             // -> stage(0) landed for ALL waves

  for (int kk = 0; kk < NK; ++kk) {
    const int cur = kk % 3;
    if (kk + 2 < NK) stage((kk + 2) % 3, kk + 2);   // buf read at kk-1 (barrier-protected)
    const short* A = &lds[cur][0][0];
    const short* Bm = &lds[cur][1][0];
    f16x8 ah[4], bh[4];
    #pragma unroll
    for (int m = 0; m < 4; ++m)
      ah[m] = *(const f16x8*)(A + (wr * 64 + m * 16) * 32 + laneoff);
    #pragma unroll
    for (int n = 0; n < 4; ++n)
      bh[n] = *(const f16x8*)(Bm + (wc * 64 + n * 16) * 32 + laneoff);
    __builtin_amdgcn_s_setprio(1);
    #pragma unroll
    for (int m = 0; m < 4; ++m)
      #pragma unroll
      for (int n = 0; n < 4; ++n)
        acc[m][n] = __builtin_amdgcn_mfma_f32_16x16x32_f16(ah[m], bh[n], acc[m][n], 0, 0, 0);
    __builtin_amdgcn_s_setprio(0);
    if (kk + 2 < NK)      VMCNT(4);   // stage(kk+1) landed; stage(kk+2) in flight
    else if (kk + 1 < NK) VMCNT(0);   // drain last prefetch
    __builtin_amdgcn_s_barrier();
  }

  const int row0 = tr * 128 + wr * 64, col0 = tc * 128 + wc * 64;
  float* Eb = EP + ((size_t)ks * BB + b) * CC * CC;
  #pragma unroll
  for (int m = 0; m < 4; ++m)
    #pragma unroll
    for (int n = 0; n < 4; ++n)
      #pragma unroll
      for (int r = 0; r < 4; ++r) {
        const int row = row0 + m * 16 + ((l >> 4) << 2) + r;   // C/D: row=(lane>>4)*4+reg
        const int col = col0 + n * 16 + (l & 15);              //      col=lane&15
        const float v = acc[m][n][r];
        Eb[(size_t)row * CC + col] = v;
        if (!diag) Eb[(size_t)col * CC + row] = v;   // mirror (L2 merges the scatter)
      }
}

// ---------------- Kernel C: att = softmax(-E) per row; pooled_out = att . mean_x ------
template <int NP>
__global__ __launch_bounds__(64) void k_softmax(
    const float* __restrict__ EP, const float* __restrict__ px,
    unsigned short* __restrict__ att, float* __restrict__ po)
{
  const int bx = blockIdx.x;                  // 8192 = b*512+c
  const int b = bx >> 9, c = bx & 511;
  const int l = threadIdx.x;
  const size_t rowoff = ((size_t)b * CC + c) * CC;
  const size_t PS = (size_t)BB * CC * CC;
  float v[8];
  float mn = 1e30f;
  #pragma unroll
  for (int i = 0; i < 8; ++i) {
    float s = EP[rowoff + l + i * 64];
    #pragma unroll
    for (int p = 1; p < NP; ++p) s += EP[p * PS + rowoff + l + i * 64];
    v[i] = s; mn = fminf(mn, s);
  }
  #pragma unroll
  for (int o = 32; o > 0; o >>= 1) mn = fminf(mn, __shfl_xor(mn, o));
  float s = 0.f;
  #pragma unroll
  for (int i = 0; i < 8; ++i) { v[i] = __expf(mn - v[i]); s += v[i]; }
  float dot = 0.f;
  const float* pxb = px + (size_t)b * CC;
  #pragma unroll
  for (int i = 0; i < 8; ++i) dot += v[i] * pxb[l + i * 64];
  #pragma unroll
  for (int o = 32; o > 0; o >>= 1) { s += __shfl_xor(s, o); dot += __shfl_xor(dot, o); }
  const float inv = 1.f / s;
  unsigned short* arow = att + ((size_t)b * CC + c) * CC;
  #pragma unroll
  for (int i = 0; i < 8; ++i) arow[l + i * 64] = f2h(v[i] * inv);
  if (l == 0) po[(size_t)b * CC + c] = dot / (s * 4096.f);
}

// ---------------- Kernel D: SE MLP -> se[b][c] -----------------------------------------
__global__ __launch_bounds__(256) void k_mlp(
    const float* __restrict__ px, const float* __restrict__ po,
    const float* __restrict__ w1, const float* __restrict__ b1,
    const float* __restrict__ w2, const float* __restrict__ b2,
    float* __restrict__ se)
{
  const int b = blockIdx.x, t = threadIdx.x;
  __shared__ float p[1024];
  __shared__ float hp[64][5];
  __shared__ float h[64];
  for (int i = t; i < 1024; i += 256)
    p[i] = (i < 512) ? px[(size_t)b * 512 + i] * (1.f / 4096.f)
                     : po[(size_t)b * 512 + i - 512];
  __syncthreads();
  {
    const int j = t >> 2, q = t & 3;
    float s = 0.f;
    const float* wr = w1 + (size_t)j * 1024 + q * 256;
    const float* pp = p + q * 256;
    for (int k = 0; k < 256; ++k) s += pp[k] * wr[k];
    hp[j][q] = s;
  }
  __syncthreads();
  if (t < 64) h[t] = fmaxf(hp[t][0] + hp[t][1] + hp[t][2] + hp[t][3] + b1[t], 0.f);
  __syncthreads();
  for (int c = t; c < 512; c += 256) {
    float s = b2[c];
    for (int j = 0; j < 64; ++j) s += h[j] * w2[(size_t)c * 64 + j];
    se[(size_t)b * 512 + c] = 1.f / (1.f + __expf(-s));
  }
}

// ---------------- Kernel E: out = att @ q, fused blend se*x + (1-se)*out --------------
// 8-wave (512t) 128x256 tile, 1024 blocks, LDS 3x24KB=72KB -> 2 blocks/CU = 16 waves/CU.
// Depth-2 pipeline: 3 gload16/wave/stage; VMCNT(3) before each barrier. Blend reads qh.
__global__ __launch_bounds__(512, 4) void k_out(
    const unsigned short* __restrict__ att,
    const unsigned short* __restrict__ qt,
    const float* __restrict__ se,
    const unsigned short* __restrict__ qh,
    float* __restrict__ out)
{
  const int bx = blockIdx.x;                      // 1024 blocks, XCD-grouped per batch
  const int xcd = bx & 7;
  const int j   = bx >> 3;                        // 0..127
  const int b   = xcd + ((j >> 6) << 3);          // 2 batches per XCD
  const int tt  = j & 63;
  const int tr = tt >> 4, tc = tt & 15;           // tr: 4 x 128 c-rows; tc: 16 x 256 n
  const int t = threadIdx.x, w = t >> 6, l = t & 63;
  const int wr = w >> 2, wc = w & 3;              // wave quadrant: 2 x 4 of 64x64

  // [buf][ A:128x32 | B:256x32 ] halves; 12288 halves = 24 KiB per buf
  __shared__ short lds[3][12288];

  const unsigned short* sA = att + (size_t)b * CC * CC + (size_t)(tr * 128) * CC;
  const unsigned short* sB = qt  + (size_t)b * NN * CC + (size_t)(tc * 256) * CC;

  const int r1 = w * 16 + (l >> 2);               // staged row (A: [0,128); B: +0/+128)
  const int kl = (((l & 3) ^ (l >> 4)) << 3);     // pre-swizzled source k offset
  const int dA  = w * 512;                        // wave-uniform LDS half-offsets
  const int dB0 = 4096 + w * 512;
  const int dB1 = 8192 + w * 512;
  const int laneoff = ((l & 15) << 5) + ((((l >> 4) ^ ((l >> 2) & 3))) << 3);

  f32x4 acc[4][4] = {};

  auto stage = [&](int buf, int kk) {             // 3 loads per wave (uniform vmcnt)
    const int k0 = kk * 32 + kl;
    gload16(sA + (size_t)r1 * CC + k0,         &lds[buf][dA]);
    gload16(sB + (size_t)r1 * CC + k0,         &lds[buf][dB0]);
    gload16(sB + (size_t)(r1 + 128) * CC + k0, &lds[buf][dB1]);
  };

  stage(0, 0);
  stage(1, 1);
  VMCNT(3);                                 // stage(0) landed (own wave)
  __builtin_amdgcn_s_barrier();             // -> landed for all waves

  for (int kk = 0; kk < 16; ++kk) {
    const int cur = kk % 3;
    if (kk + 2 < 16) stage((kk + 2) % 3, kk + 2);
    const short* A  = &lds[cur][0];
    const short* Bm = &lds[cur][4096];
    f16x8 af[4], bf[4];
    #pragma unroll
    for (int m = 0; m < 4; ++m) af[m] = *(const f16x8*)(A  + (wr * 64 + m * 16) * 32 + laneoff);
    #pragma unroll
    for (int n = 0; n < 4; ++n) bf[n] = *(const f16x8*)(Bm + (wc * 64 + n * 16) * 32 + laneoff);
    __builtin_amdgcn_s_setprio(1);
    #pragma unroll
    for (int m = 0; m < 4; ++m)
      #pragma unroll
      for (int n = 0; n < 4; ++n)
        acc[m][n] = __builtin_amdgcn_mfma_f32_16x16x32_f16(af[m], bf[n], acc[m][n], 0, 0, 0);
    __builtin_amdgcn_s_setprio(0);
    if (kk + 2 < 16)      VMCNT(3);   // stage(kk+1) landed; stage(kk+2) in flight
    else if (kk + 1 < 16) VMCNT(0);
    __builtin_amdgcn_s_barrier();
  }

  // ---- epilogue: per-wave LDS slab (16 rows x 68 pitch), float4-coalesced IO ----
  float* slab = (float*)(&lds[0][0]) + w * (16 * 68);   // 8 x 4352 B = 34.8 KB <= 72 KB
  const int row0 = tr * 128 + wr * 64, col0q = tc * 256 + wc * 64;
  const size_t xb = (size_t)b * CC * NN;
  const float* seb = se + (size_t)b * CC;
  #pragma unroll
  for (int m = 0; m < 4; ++m) {
    #pragma unroll
    for (int n = 0; n < 4; ++n)
      #pragma unroll
      for (int r = 0; r < 4; ++r)
        slab[(((l >> 4) << 2) + r) * 68 + n * 16 + (l & 15)] = acc[m][n][r];
    #pragma unroll
    for (int it = 0; it < 4; ++it) {
      const int rl = (it << 2) + (l >> 4);
      const int c  = row0 + m * 16 + rl;
      const int n4 = (l & 15) << 2;
      const float4 a = *(const float4*)&slab[rl * 68 + n4];
      const float sv = seb[c];
      const float om = 1.f - sv;
      const size_t go = xb + (size_t)c * NN + col0q + n4;
      const ushort4 hx = *(const ushort4*)(qh + go);
      float4 o;
      o.x = sv * h2f(hx.x) + om * a.x;
      o.y = sv * h2f(hx.y) + om * a.y;
      o.z = sv * h2f(hx.z) + om * a.z;
      o.w = sv * h2f(hx.w) + om * a.w;
      *(float4*)(out + go) = o;
    }
  }
}

// ---------------------------------------------------------------------------------------
extern "C" void kernel_launch(void* const* d_in, const int* in_sizes, int n_in,
                              void* d_out, int out_size, void* d_ws, size_t ws_size,
                              hipStream_t stream) {
  (void)in_sizes; (void)n_in; (void)out_size;
  const float* x  = (const float*)d_in[0];
  const float* w1 = (const float*)d_in[1];
  const float* b1 = (const float*)d_in[2];
  const float* w2 = (const float*)d_in[3];
  const float* b2 = (const float*)d_in[4];
  float* out = (float*)d_out;

  const size_t O_QH  = 0;                       // 67,108,864 (fp16 q)
  const size_t O_QT  = 67108864;                // 67,108,864 (fp16 qT)
  const size_t O_EP  = 134217728;               // KSPLIT x 16,777,216 (fp32 E partials)
  const size_t EPSZ1 = 16777216;

  // tail: att(8,388,608) + part(1,048,576) + px/po/se(3*32768)
  const size_t TAIL = 8388608 + 1048576 + 3 * 32768;     // 9,535,488
  const size_t NEED1 = O_EP + 1 * EPSZ1 + TAIL;          // 160,530,432
  const size_t NEED2 = O_EP + 2 * EPSZ1 + TAIL;          // 177,307,648
  const size_t NEED4 = O_EP + 4 * EPSZ1 + TAIL;          // 210,862,080

  if (ws_size < NEED1) return;   // fail loudly (output stays poisoned)
  const int ksplit = (ws_size >= NEED4) ? 4 : (ws_size >= NEED2) ? 2 : 1;

  char* ws = (char*)d_ws;
  unsigned short* qh  = (unsigned short*)(ws + O_QH);
  unsigned short* qt  = (unsigned short*)(ws + O_QT);
  float*          EP  = (float*)(ws + O_EP);
  char* tail          = ws + O_EP + (size_t)ksplit * EPSZ1;
  unsigned short* att = (unsigned short*)(tail);
  float*          part= (float*)(tail + 8388608);
  float*          px  = (float*)(tail + 9437184);
  float*          po  = (float*)(tail + 9469952);
  float*          se  = (float*)(tail + 9502720);

  k_convert<<<dim3(32, 8, 16), 256, 0, stream>>>(x, qh, qt, part);
  k_sumpart<<<32, 256, 0, stream>>>(part, px);
  if (ksplit == 4) {
    k_energy<4><<<640, 256, 0, stream>>>(qh, EP);
    k_softmax<4><<<8192, 64, 0, stream>>>(EP, px, att, po);
  } else if (ksplit == 2) {
    k_energy<2><<<320, 256, 0, stream>>>(qh, EP);
    k_softmax<2><<<8192, 64, 0, stream>>>(EP, px, att, po);
  } else {
    k_energy<1><<<160, 256, 0, stream>>>(qh, EP);
    k_softmax<1><<<8192, 64, 0, stream>>>(EP, px, att, po);
  }
  k_mlp<<<16, 256, 0, stream>>>(px, po, w1, b1, w2, b2, se);
  k_out<<<1024, 512, 0, stream>>>(att, qt, se, qh, out);
}

// Round 10
// 212.685 us; speedup vs baseline: 1.4847x; 1.0211x over previous
//
#include <hip/hip_runtime.h>
#include <cstdint>
#include <cstddef>

#define BB 16
#define CC 512
#define NN 4096

typedef __attribute__((ext_vector_type(4))) float f32x4;
typedef __attribute__((ext_vector_type(8))) _Float16 f16x8;

#define VMCNT(n) asm volatile("s_waitcnt vmcnt(" #n ")" ::: "memory")

__device__ __forceinline__ unsigned short f2h(float f) {
  _Float16 h = (_Float16)f;                       // v_cvt_f16_f32, RTN
  return __builtin_bit_cast(unsigned short, h);
}
__device__ __forceinline__ float h2f(unsigned short u) {
  return (float)__builtin_bit_cast(_Float16, u);
}

// async global->LDS, 16B per lane. LDS dest must be wave-uniform base; HW adds lane*16.
__device__ __forceinline__ void gload16(const unsigned short* g, short* l) {
  __builtin_amdgcn_global_load_lds(
      (const __attribute__((address_space(1))) unsigned int*)g,
      (__attribute__((address_space(3))) unsigned int*)(__attribute__((address_space(3))) short*)l,
      16, 0, 0);
}

// ---------------- Kernel A: x -> fp16 q, transposed q, row partial sums ---------------
// 4096 blocks, ~19 KB LDS -> 8 blocks/CU. MLP fix: 4 independent float4 loads in
// flight per super-iteration (was 1 dependent load->convert->store chain; 2.6 TB/s).
__global__ __launch_bounds__(256) void k_convert(
    const float* __restrict__ x,
    unsigned short* __restrict__ qh,
    unsigned short* __restrict__ qt,
    float* __restrict__ part)
{
  const int nt = blockIdx.x;     // 32 tiles of 128 n
  const int ct = blockIdx.y;     // 8 tiles of 64 c
  const int b  = blockIdx.z;
  const int c0 = ct << 6;
  const int n0 = nt << 7;
  const int t  = threadIdx.x;
  const int w  = t >> 6;
  const int l  = t & 63;

  __shared__ unsigned short lt[128 * 65];   // [n_local][c_local], pitch 65 (bank spread)
  __shared__ float fs[64][8];               // per-row quad partials

  const size_t xb = (size_t)b * CC * NN;
  const int nl = (l & 31) << 2;             // n offset in tile [0,128)

  #pragma unroll
  for (int ii = 0; ii < 2; ++ii) {
    float4 v[4];
    int rr[4];
    size_t offs[4];
    #pragma unroll
    for (int i2 = 0; i2 < 4; ++i2) {
      const int i = ii * 4 + i2;
      rr[i2] = (i << 3) + (w << 1) + (l >> 5);         // c row in tile
      offs[i2] = xb + (size_t)(c0 + rr[i2]) * NN + n0 + nl;
      v[i2] = *(const float4*)(x + offs[i2]);          // 4 independent loads in flight
    }
    #pragma unroll
    for (int i2 = 0; i2 < 4; ++i2) {
      const int r = rr[i2];
      const unsigned short h0 = f2h(v[i2].x), h1 = f2h(v[i2].y),
                           h2 = f2h(v[i2].z), h3 = f2h(v[i2].w);
      *(ushort4*)(qh + offs[i2]) = make_ushort4(h0, h1, h2, h3);
      lt[(nl + 0) * 65 + r] = h0;
      lt[(nl + 1) * 65 + r] = h1;
      lt[(nl + 2) * 65 + r] = h2;
      lt[(nl + 3) * 65 + r] = h3;
      float s = v[i2].x + v[i2].y + v[i2].z + v[i2].w;
      s += __shfl_xor(s, 1);
      s += __shfl_xor(s, 2);                           // quad sum (same row)
      if ((l & 3) == 0) fs[r][(l & 31) >> 2] = s;
    }
  }
  __syncthreads();
  if (t < 64) {
    float s = 0.f;
    #pragma unroll
    for (int qd = 0; qd < 8; ++qd) s += fs[t][qd];
    part[((size_t)b * CC + c0 + t) * 32 + nt] = s;
  }

  // transposed write: qt[b][n][c]
  #pragma unroll
  for (int p = 0; p < 4; ++p) {
    const int n   = (p << 5) + (t >> 3);
    const int cc8 = (t & 7) << 3;
    const unsigned short* e = &lt[n * 65 + cc8];
    uint4 pk;
    pk.x = (unsigned)e[0] | ((unsigned)e[1] << 16);
    pk.y = (unsigned)e[2] | ((unsigned)e[3] << 16);
    pk.z = (unsigned)e[4] | ((unsigned)e[5] << 16);
    pk.w = (unsigned)e[6] | ((unsigned)e[7] << 16);
    *(uint4*)(qt + ((size_t)b * NN + n0 + n) * CC + c0 + cc8) = pk;
  }
}

// ---------------- Kernel A2: sum row partials -> pooled_x raw sums --------------------
__global__ __launch_bounds__(256) void k_sumpart(const float* __restrict__ part,
                                                 float* __restrict__ px)
{
  const int g = blockIdx.x * 256 + threadIdx.x;   // 0..8191 = b*512+c
  float s = 0.f;
  #pragma unroll
  for (int i = 0; i < 32; ++i) s += part[(size_t)g * 32 + i];
  px[g] = s;
}

// ---------------- Kernel B: energy = q.qT, fp16, SYMMETRIC upper-tri ------------------
// 128x128 tile, 4 waves, BK=32, 48 KiB LDS (3 blocks/CU). Depth-2 pipeline (3 bufs):
// VMCNT(4) before each barrier -> stage(kk+1) landed for all waves; stage(kk+2) stays
// in flight across the barrier (T4, sound cross-wave).
template <int KSPLIT>
__global__ __launch_bounds__(256, 3) void k_energy(
    const unsigned short* __restrict__ qh,
    float* __restrict__ EP)
{
  const int bx  = blockIdx.x;               // 160*KSPLIT blocks
  const int xcd = bx & 7;
  const int j   = bx >> 3;
  const int gi  = j / 10;
  const int t10 = j % 10;
  const int g   = xcd + (gi << 3);          // group = b*KSPLIT+ks, grouped per XCD
  const int b   = g / KSPLIT;
  const int ks  = g % KSPLIT;
  int tr, tc;
  if (t10 < 4)      { tr = 0; tc = t10; }
  else if (t10 < 7) { tr = 1; tc = t10 - 3; }
  else if (t10 < 9) { tr = 2; tc = t10 - 5; }
  else              { tr = 3; tc = 3; }
  const bool diag = (tr == tc);
  const int kbase = ks * (NN / KSPLIT);
  const int NK    = 128 / KSPLIT;           // K-steps of 32

  const int t = threadIdx.x, w = t >> 6, l = t & 63;
  const int wr = w >> 1, wc = w & 1;

  __shared__ short lds[3][2][128 * 32];     // [buf][A,B] = 48 KiB

  const size_t qoff = (size_t)b * CC * NN;
  const unsigned short* sA = qh + qoff + (size_t)(tr * 128) * NN;
  const unsigned short* sB = diag ? sA : qh + qoff + (size_t)(tc * 128) * NN;

  const int r1 = w * 16 + (l >> 2);
  const int kl = (((l & 3) ^ (l >> 4)) << 3);          // pre-swizzled source k offset
  const int d1 = w * 512;
  const int d2 = 2048 + w * 512;
  const int laneoff = ((l & 15) << 5) + ((((l >> 4) ^ ((l >> 2) & 3))) << 3);

  f32x4 acc[4][4] = {};

  auto stage = [&](int buf, int kk) {       // always 4 loads (uniform vmcnt)
    const int k0 = kbase + kk * 32 + kl;
    gload16(sA + (size_t)r1 * NN + k0,        &lds[buf][0][d1]);
    gload16(sA + (size_t)(r1 + 64) * NN + k0, &lds[buf][0][d2]);
    gload16(sB + (size_t)r1 * NN + k0,        &lds[buf][1][d1]);
    gload16(sB + (size_t)(r1 + 64) * NN + k0, &lds[buf][1][d2]);
  };

  stage(0, 0);
  stage(1, 1);
  VMCNT(4);
  __builtin_amdgcn_s_barrier();

  for (int kk = 0; kk < NK; ++kk) {
    const int cur = kk % 3;
    if (kk + 2 < NK) stage((kk + 2) % 3, kk + 2);
    const short* A = &lds[cur][0][0];
    const short* Bm = &lds[cur][1][0];
    f16x8 ah[4], bh[4];
    #pragma unroll
    for (int m = 0; m < 4; ++m)
      ah[m] = *(const f16x8*)(A + (wr * 64 + m * 16) * 32 + laneoff);
    #pragma unroll
    for (int n = 0; n < 4; ++n)
      bh[n] = *(const f16x8*)(Bm + (wc * 64 + n * 16) * 32 + laneoff);
    __builtin_amdgcn_s_setprio(1);
    #pragma unroll
    for (int m = 0; m < 4; ++m)
      #pragma unroll
      for (int n = 0; n < 4; ++n)
        acc[m][n] = __builtin_amdgcn_mfma_f32_16x16x32_f16(ah[m], bh[n], acc[m][n], 0, 0, 0);
    __builtin_amdgcn_s_setprio(0);
    if (kk + 2 < NK)      VMCNT(4);
    else if (kk + 1 < NK) VMCNT(0);
    __builtin_amdgcn_s_barrier();
  }

  const int row0 = tr * 128 + wr * 64, col0 = tc * 128 + wc * 64;
  float* Eb = EP + ((size_t)ks * BB + b) * CC * CC;
  #pragma unroll
  for (int m = 0; m < 4; ++m)
    #pragma unroll
    for (int n = 0; n < 4; ++n)
      #pragma unroll
      for (int r = 0; r < 4; ++r) {
        const int row = row0 + m * 16 + ((l >> 4) << 2) + r;
        const int col = col0 + n * 16 + (l & 15);
        const float v = acc[m][n][r];
        Eb[(size_t)row * CC + col] = v;
        if (!diag) Eb[(size_t)col * CC + row] = v;
      }
}

// ---------------- Kernel C: att = softmax(-E) per row; pooled_out = att . mean_x ------
template <int NP>
__global__ __launch_bounds__(64) void k_softmax(
    const float* __restrict__ EP, const float* __restrict__ px,
    unsigned short* __restrict__ att, float* __restrict__ po)
{
  const int bx = blockIdx.x;                  // 8192 = b*512+c
  const int b = bx >> 9, c = bx & 511;
  const int l = threadIdx.x;
  const size_t rowoff = ((size_t)b * CC + c) * CC;
  const size_t PS = (size_t)BB * CC * CC;
  float v[8];
  float mn = 1e30f;
  #pragma unroll
  for (int i = 0; i < 8; ++i) {
    float s = EP[rowoff + l + i * 64];
    #pragma unroll
    for (int p = 1; p < NP; ++p) s += EP[p * PS + rowoff + l + i * 64];
    v[i] = s; mn = fminf(mn, s);
  }
  #pragma unroll
  for (int o = 32; o > 0; o >>= 1) mn = fminf(mn, __shfl_xor(mn, o));
  float s = 0.f;
  #pragma unroll
  for (int i = 0; i < 8; ++i) { v[i] = __expf(mn - v[i]); s += v[i]; }
  float dot = 0.f;
  const float* pxb = px + (size_t)b * CC;
  #pragma unroll
  for (int i = 0; i < 8; ++i) dot += v[i] * pxb[l + i * 64];
  #pragma unroll
  for (int o = 32; o > 0; o >>= 1) { s += __shfl_xor(s, o); dot += __shfl_xor(dot, o); }
  const float inv = 1.f / s;
  unsigned short* arow = att + ((size_t)b * CC + c) * CC;
  #pragma unroll
  for (int i = 0; i < 8; ++i) arow[l + i * 64] = f2h(v[i] * inv);
  if (l == 0) po[(size_t)b * CC + c] = dot / (s * 4096.f);
}

// ---------------- Kernel D: SE MLP -> se[b][c] -----------------------------------------
__global__ __launch_bounds__(256) void k_mlp(
    const float* __restrict__ px, const float* __restrict__ po,
    const float* __restrict__ w1, const float* __restrict__ b1,
    const float* __restrict__ w2, const float* __restrict__ b2,
    float* __restrict__ se)
{
  const int b = blockIdx.x, t = threadIdx.x;
  __shared__ float p[1024];
  __shared__ float hp[64][5];
  __shared__ float h[64];
  for (int i = t; i < 1024; i += 256)
    p[i] = (i < 512) ? px[(size_t)b * 512 + i] * (1.f / 4096.f)
                     : po[(size_t)b * 512 + i - 512];
  __syncthreads();
  {
    const int j = t >> 2, q = t & 3;
    float s = 0.f;
    const float* wr = w1 + (size_t)j * 1024 + q * 256;
    const float* pp = p + q * 256;
    for (int k = 0; k < 256; ++k) s += pp[k] * wr[k];
    hp[j][q] = s;
  }
  __syncthreads();
  if (t < 64) h[t] = fmaxf(hp[t][0] + hp[t][1] + hp[t][2] + hp[t][3] + b1[t], 0.f);
  __syncthreads();
  for (int c = t; c < 512; c += 256) {
    float s = b2[c];
    for (int j = 0; j < 64; ++j) s += h[j] * w2[(size_t)c * 64 + j];
    se[(size_t)b * 512 + c] = 1.f / (1.f + __expf(-s));
  }
}

// ---------------- Kernel E: out = att @ q, fused blend se*x + (1-se)*out --------------
// 8-wave (512t) 128x256 tile, 1024 blocks, LDS 3x24KB=72KB -> 2 blocks/CU.
// Depth-2 pipeline: 3 gload16/wave/stage; VMCNT(3) before each barrier. Blend reads qh.
__global__ __launch_bounds__(512, 4) void k_out(
    const unsigned short* __restrict__ att,
    const unsigned short* __restrict__ qt,
    const float* __restrict__ se,
    const unsigned short* __restrict__ qh,
    float* __restrict__ out)
{
  const int bx = blockIdx.x;                      // 1024 blocks, XCD-grouped per batch
  const int xcd = bx & 7;
  const int j   = bx >> 3;                        // 0..127
  const int b   = xcd + ((j >> 6) << 3);          // 2 batches per XCD
  const int tt  = j & 63;
  const int tr = tt >> 4, tc = tt & 15;           // tr: 4 x 128 c-rows; tc: 16 x 256 n
  const int t = threadIdx.x, w = t >> 6, l = t & 63;
  const int wr = w >> 2, wc = w & 3;              // wave quadrant: 2 x 4 of 64x64

  // [buf][ A:128x32 | B:256x32 ] halves; 12288 halves = 24 KiB per buf
  __shared__ short lds[3][12288];

  const unsigned short* sA = att + (size_t)b * CC * CC + (size_t)(tr * 128) * CC;
  const unsigned short* sB = qt  + (size_t)b * NN * CC + (size_t)(tc * 256) * CC;

  const int r1 = w * 16 + (l >> 2);               // staged row (A: [0,128); B: +0/+128)
  const int kl = (((l & 3) ^ (l >> 4)) << 3);     // pre-swizzled source k offset
  const int dA  = w * 512;                        // wave-uniform LDS half-offsets
  const int dB0 = 4096 + w * 512;
  const int dB1 = 8192 + w * 512;
  const int laneoff = ((l & 15) << 5) + ((((l >> 4) ^ ((l >> 2) & 3))) << 3);

  f32x4 acc[4][4] = {};

  auto stage = [&](int buf, int kk) {             // 3 loads per wave (uniform vmcnt)
    const int k0 = kk * 32 + kl;
    gload16(sA + (size_t)r1 * CC + k0,         &lds[buf][dA]);
    gload16(sB + (size_t)r1 * CC + k0,         &lds[buf][dB0]);
    gload16(sB + (size_t)(r1 + 128) * CC + k0, &lds[buf][dB1]);
  };

  stage(0, 0);
  stage(1, 1);
  VMCNT(3);                                 // stage(0) landed (own wave)
  __builtin_amdgcn_s_barrier();             // -> landed for all waves

  for (int kk = 0; kk < 16; ++kk) {
    const int cur = kk % 3;
    if (kk + 2 < 16) stage((kk + 2) % 3, kk + 2);
    const short* A  = &lds[cur][0];
    const short* Bm = &lds[cur][4096];
    f16x8 af[4], bf[4];
    #pragma unroll
    for (int m = 0; m < 4; ++m) af[m] = *(const f16x8*)(A  + (wr * 64 + m * 16) * 32 + laneoff);
    #pragma unroll
    for (int n = 0; n < 4; ++n) bf[n] = *(const f16x8*)(Bm + (wc * 64 + n * 16) * 32 + laneoff);
    __builtin_amdgcn_s_setprio(1);
    #pragma unroll
    for (int m = 0; m < 4; ++m)
      #pragma unroll
      for (int n = 0; n < 4; ++n)
        acc[m][n] = __builtin_amdgcn_mfma_f32_16x16x32_f16(af[m], bf[n], acc[m][n], 0, 0, 0);
    __builtin_amdgcn_s_setprio(0);
    if (kk + 2 < 16)      VMCNT(3);   // stage(kk+1) landed; stage(kk+2) in flight
    else if (kk + 1 < 16) VMCNT(0);
    __builtin_amdgcn_s_barrier();
  }

  // ---- epilogue: per-wave LDS slab (16 rows x 68 pitch), float4-coalesced IO ----
  float* slab = (float*)(&lds[0][0]) + w * (16 * 68);
  const int row0 = tr * 128 + wr * 64, col0q = tc * 256 + wc * 64;
  const size_t xb = (size_t)b * CC * NN;
  const float* seb = se + (size_t)b * CC;
  #pragma unroll
  for (int m = 0; m < 4; ++m) {
    #pragma unroll
    for (int n = 0; n < 4; ++n)
      #pragma unroll
      for (int r = 0; r < 4; ++r)
        slab[(((l >> 4) << 2) + r) * 68 + n * 16 + (l & 15)] = acc[m][n][r];
    #pragma unroll
    for (int it = 0; it < 4; ++it) {
      const int rl = (it << 2) + (l >> 4);
      const int c  = row0 + m * 16 + rl;
      const int n4 = (l & 15) << 2;
      const float4 a = *(const float4*)&slab[rl * 68 + n4];
      const float sv = seb[c];
      const float om = 1.f - sv;
      const size_t go = xb + (size_t)c * NN + col0q + n4;
      const ushort4 hx = *(const ushort4*)(qh + go);
      float4 o;
      o.x = sv * h2f(hx.x) + om * a.x;
      o.y = sv * h2f(hx.y) + om * a.y;
      o.z = sv * h2f(hx.z) + om * a.z;
      o.w = sv * h2f(hx.w) + om * a.w;
      *(float4*)(out + go) = o;
    }
  }
}

// ---------------------------------------------------------------------------------------
extern "C" void kernel_launch(void* const* d_in, const int* in_sizes, int n_in,
                              void* d_out, int out_size, void* d_ws, size_t ws_size,
                              hipStream_t stream) {
  (void)in_sizes; (void)n_in; (void)out_size;
  const float* x  = (const float*)d_in[0];
  const float* w1 = (const float*)d_in[1];
  const float* b1 = (const float*)d_in[2];
  const float* w2 = (const float*)d_in[3];
  const float* b2 = (const float*)d_in[4];
  float* out = (float*)d_out;

  const size_t O_QH  = 0;                       // 67,108,864 (fp16 q)
  const size_t O_QT  = 67108864;                // 67,108,864 (fp16 qT)
  const size_t O_EP  = 134217728;               // KSPLIT x 16,777,216 (fp32 E partials)
  const size_t EPSZ1 = 16777216;

  // tail: att(8,388,608) + part(1,048,576) + px/po/se(3*32768)
  const size_t TAIL = 8388608 + 1048576 + 3 * 32768;     // 9,535,488
  const size_t NEED1 = O_EP + 1 * EPSZ1 + TAIL;
  const size_t NEED2 = O_EP + 2 * EPSZ1 + TAIL;
  const size_t NEED4 = O_EP + 4 * EPSZ1 + TAIL;

  if (ws_size < NEED1) return;   // fail loudly (output stays poisoned)
  const int ksplit = (ws_size >= NEED4) ? 4 : (ws_size >= NEED2) ? 2 : 1;

  char* ws = (char*)d_ws;
  unsigned short* qh  = (unsigned short*)(ws + O_QH);
  unsigned short* qt  = (unsigned short*)(ws + O_QT);
  float*          EP  = (float*)(ws + O_EP);
  char* tail          = ws + O_EP + (size_t)ksplit * EPSZ1;
  unsigned short* att = (unsigned short*)(tail);
  float*          part= (float*)(tail + 8388608);
  float*          px  = (float*)(tail + 9437184);
  float*          po  = (float*)(tail + 9469952);
  float*          se  = (float*)(tail + 9502720);

  k_convert<<<dim3(32, 8, 16), 256, 0, stream>>>(x, qh, qt, part);
  k_sumpart<<<32, 256, 0, stream>>>(part, px);
  if (ksplit == 4) {
    k_energy<4><<<640, 256, 0, stream>>>(qh, EP);
    k_softmax<4><<<8192, 64, 0, stream>>>(EP, px, att, po);
  } else if (ksplit == 2) {
    k_energy<2><<<320, 256, 0, stream>>>(qh, EP);
    k_softmax<2><<<8192, 64, 0, stream>>>(EP, px, att, po);
  } else {
    k_energy<1><<<160, 256, 0, stream>>>(qh, EP);
    k_softmax<1><<<8192, 64, 0, stream>>>(EP, px, att, po);
  }
  k_mlp<<<16, 256, 0, stream>>>(px, po, w1, b1, w2, b2, se);
  k_out<<<1024, 512, 0, stream>>>(att, qt, se, qh, out);
}